// Round 12
// baseline (130.206 us; speedup 1.0000x reference)
//
#include <hip/hip_runtime.h>
#include <stdint.h>

typedef __attribute__((ext_vector_type(8))) short short8;
typedef __attribute__((ext_vector_type(4))) float f32x4;
typedef __attribute__((ext_vector_type(16))) float f32x16;
typedef __attribute__((ext_vector_type(4))) int i32x4;
typedef __attribute__((ext_vector_type(2))) int i32x2;

#define MFMA16(a, b, c) __builtin_amdgcn_mfma_f32_16x16x32_bf16((a), (b), (c), 0, 0, 0)
#define MFMA32(a, b, c) __builtin_amdgcn_mfma_f32_32x32x16_bf16((a), (b), (c), 0, 0, 0)

typedef __attribute__((address_space(1))) const void GVoid;
typedef __attribute__((address_space(3))) void LVoid;
#define GLDS16(g, l) __builtin_amdgcn_global_load_lds((GVoid*)(g), (LVoid*)(l), 16, 0, 0)

#define L2E 1.4426950408889634f

__device__ __forceinline__ unsigned short f2bf(float f) {
  unsigned int u = __builtin_bit_cast(unsigned int, f);
  u += 0x7fffu + ((u >> 16) & 1u);   // RNE (finite values only)
  return (unsigned short)(u >> 16);
}
__device__ __forceinline__ float bf2f(unsigned short u) {
  return __builtin_bit_cast(float, (unsigned int)u << 16);
}

// permlane32_swap via builtin: two simultaneously-live results -> distinct regs
// guaranteed (inline-asm "+v","+v" self-swap was R3's bug).
__device__ __forceinline__ i32x2 pls(int a, int b) {
  return __builtin_amdgcn_permlane32_swap(a, b, false, false);
}
__device__ __forceinline__ float fasf(int x) { return __builtin_bit_cast(float, x); }
__device__ __forceinline__ int iasi(float x) { return __builtin_bit_cast(int, x); }

__device__ __forceinline__ int cvtpk(float lo, float hi) {
  int d;
  asm("v_cvt_pk_bf16_f32 %0, %1, %2" : "=v"(d) : "v"(lo), "v"(hi));
  return d;
}

// ---------------------------------------------------------------------------
// Kernel 1: Q/K/V projections, written in MFMA-fragment-ready tiled layouts
// (32-row tiles):
//   Q2/K2: elem[(b*128 + tile)*4096 + kt*512 + ((h>>3)&1)*256 + (s&31)*8 + (h&7)]
//   V2:    elem[(b*128 + tile)*4096 + ((s>>4)&1)*2048 + (d>>5)*512
//               + ((s>>3)&1)*256 + (d&31)*8 + (s&7)]
//   Wo2:   elem[((oc>>5)*8 + (h>>4))*512 + ((h>>3)&1)*256 + (oc&31)*8 + (h&7)]
// Q pre-scaled by 1/sqrt(128). Q2/K2 written via LDS-transpose staging so all
// global stores are coalesced 16B chunks (was: 32 scalar 2B stores/lane).
// ---------------------------------------------------------------------------
__global__ __launch_bounds__(256) void k_proj(
    const float* __restrict__ x,
    const float* __restrict__ Wq, const float* __restrict__ bq,
    const float* __restrict__ Wk, const float* __restrict__ bk,
    const float* __restrict__ Wv, const float* __restrict__ bv,
    const float* __restrict__ Wo,
    unsigned short* __restrict__ Q2, unsigned short* __restrict__ K2,
    unsigned short* __restrict__ V2, unsigned short* __restrict__ Wo2)
{
  __shared__ __align__(16) unsigned short wt[128 * 128];  // swizzled W^T, 32KB
  __shared__ __align__(16) unsigned short st[64 * 136];   // store-stage, 17KB
  const int tid  = threadIdx.x;
  const int lane = tid & 63;
  const int wid  = tid >> 6;
  const int l15  = lane & 15;
  const int g    = lane >> 4;
  const int r0   = blockIdx.x * 64 + wid * 16;

  if (blockIdx.x == 0) {
    for (int e = tid; e < 16384; e += 256) {
      int j = e & 7, ln = (e >> 3) & 63, kt = (e >> 9) & 7, dt = e >> 12;
      int h = kt * 16 + (ln >> 5) * 8 + j, oc = dt * 32 + (ln & 31);
      Wo2[e] = f2bf(Wo[h * 128 + oc]);
    }
  }

  short8 af[4];
  {
    const float* xp = x + (r0 + l15) * 128 + g * 8;
#pragma unroll
    for (int kt = 0; kt < 4; ++kt) {
      float4 v0 = *(const float4*)(xp + kt * 32);
      float4 v1 = *(const float4*)(xp + kt * 32 + 4);
      short8 a;
      a[0] = (short)f2bf(v0.x); a[1] = (short)f2bf(v0.y);
      a[2] = (short)f2bf(v0.z); a[3] = (short)f2bf(v0.w);
      a[4] = (short)f2bf(v1.x); a[5] = (short)f2bf(v1.y);
      a[6] = (short)f2bf(v1.z); a[7] = (short)f2bf(v1.w);
      af[kt] = a;
    }
  }

  const float* Ws[3] = {Wq, Wk, Wv};
  const float* bs[3] = {bq, bk, bv};

  for (int wI = 0; wI < 3; ++wI) {
    __syncthreads();
    const float* W = Ws[wI];
    for (int i = 0; i < 64; ++i) {
      int idx = i * 256 + tid;
      int k = idx >> 7, n = idx & 127;
      int cs = (k >> 3) ^ (n & 7);
      wt[n * 128 + cs * 8 + (k & 7)] = f2bf(W[idx]);
    }
    __syncthreads();

    float bias[8];
#pragma unroll
    for (int nt = 0; nt < 8; ++nt) bias[nt] = bs[wI][nt * 16 + l15];

    f32x4 acc[8];
#pragma unroll
    for (int nt = 0; nt < 8; ++nt) acc[nt] = (f32x4){0.f, 0.f, 0.f, 0.f};

#pragma unroll
    for (int nt = 0; nt < 8; ++nt) {
      const int n = nt * 16 + l15;
#pragma unroll
      for (int ks = 0; ks < 4; ++ks) {
        int cs = (ks * 4 + g) ^ (n & 7);
        short8 bf = *(const short8*)&wt[n * 128 + cs * 8];
        acc[nt] = MFMA16(af[ks], bf, acc[nt]);
      }
    }

    // D layout: col = nt*16 + l15 (h/d dim), row m = r0 + g*4 + r (s dim)
    if (wI < 2) {
      const float sc = (wI == 0) ? 0.08838834764831845f : 1.0f;  // 1/sqrt(128)
      // stage to padded LDS tile [64 rows][136 cols]
#pragma unroll
      for (int nt = 0; nt < 8; ++nt) {
        int col = nt * 16 + l15;
#pragma unroll
        for (int r = 0; r < 4; ++r)
          st[(wid * 16 + g * 4 + r) * 136 + col] = f2bf((acc[nt][r] + bias[nt]) * sc);
      }
      __syncthreads();
      // coalesced fragment-order writes: 1024 chunks of 16B, 4 per thread
      unsigned short* Og = (wI == 0) ? Q2 : K2;
#pragma unroll
      for (int c4 = 0; c4 < 4; ++c4) {
        int c = c4 * 256 + tid;
        int T = c >> 9, cc = c & 511;
        int kt = cc >> 6, hib = (cc >> 5) & 1, s32 = cc & 31;
        int m0 = blockIdx.x * 64 + T * 32;
        int bb = m0 >> 12, tile = (m0 & 4095) >> 5;
        short8 v = *(const short8*)&st[(T * 32 + s32) * 136 + kt * 16 + hib * 8];
        *(short8*)&Og[(size_t)(bb * 128 + tile) * 4096 + cc * 8] = v;
      }
    } else {
#pragma unroll
      for (int nt = 0; nt < 8; ++nt) {
        int col = nt * 16 + l15;
        int m0 = r0 + g * 4;
        int bb = m0 >> 12, srow = m0 & 4095;
        int idx = (bb * 128 + (srow >> 5)) * 4096 + ((srow >> 4) & 1) * 2048 +
                  (col >> 5) * 512 + ((srow >> 3) & 1) * 256 + (col & 31) * 8 +
                  (srow & 7);
        ushort4 pk;
        pk.x = f2bf(acc[nt][0] + bias[nt]);
        pk.y = f2bf(acc[nt][1] + bias[nt]);
        pk.z = f2bf(acc[nt][2] + bias[nt]);
        pk.w = f2bf(acc[nt][3] + bias[nt]);
        *(ushort4*)&V2[idx] = pk;
      }
    }
  }
}

// ---------------------------------------------------------------------------
// Kernel 2: flash attention partials, LDS-shared KV, split-KV over blocks.
// Grid 256 = (4 b) x (16 q-supertiles of 256 rows) x (4 KV quarters).
// 512 thr = 8 waves x 32 q-rows; KVBLK=64, 16 iters over the 1024-kv quarter.
// DOUBLE-buffered 32KB K+V tile (global_load_lds, 1-ahead prefetch, counted
// vmcnt(4)); two raw s_barriers per iter: leading = "all slices of tile t
// landed", trailing = "all waves done reading buf" (frees it for restage at
// t+1). 65KB LDS -> 2 blocks/CU (vs R11 triple-buffer's 99KB / 1 block).
// Output: partial O as bf16 A-fragment image PA + (m,l) in ML2.
// ---------------------------------------------------------------------------
__global__ __launch_bounds__(512, 4) void k_attn(
    const unsigned short* __restrict__ Q2,
    const unsigned short* __restrict__ K2,
    const unsigned short* __restrict__ V2,
    unsigned short* __restrict__ PA,
    float2* __restrict__ ML2)
{
  __shared__ __align__(16) char smem[66560];   // 2 x 32KB bufs + 1KB RBUF
  const int tid = threadIdx.x, lane = tid & 63, wid = tid >> 6;
  const int rr = lane & 31, hi = lane >> 5;
  // XCD-aware: batch b pinned to XCD pair {2b,2b+1}
  const int p = blockIdx.x;
  const int b = (p & 7) >> 1;
  const int idx = ((p >> 3) << 1) | (p & 1);   // 0..63
  const int qt = idx >> 2, kvq = idx & 3;
  const int q0tile = qt * 8 + wid;             // 32q-tile index 0..127

  // Q fragments (pre-scaled): 8 coalesced 1KB loads
  short8 qf[8];
  {
    const unsigned short* qp = Q2 + (size_t)(b * 128 + q0tile) * 4096 + lane * 8;
#pragma unroll
    for (int kt = 0; kt < 8; ++kt) qf[kt] = *(const short8*)(qp + kt * 512);
  }

  // staging sources: thread tid stages 4 x 16B chunks -> K tile0/1, V tile0/1
  const unsigned short* gsrc[4];
  gsrc[0] = K2 + (size_t)(b * 128 + kvq * 32 + 0) * 4096 + tid * 8;
  gsrc[1] = K2 + (size_t)(b * 128 + kvq * 32 + 1) * 4096 + tid * 8;
  gsrc[2] = V2 + (size_t)(b * 128 + kvq * 32 + 0) * 4096 + tid * 8;
  gsrc[3] = V2 + (size_t)(b * 128 + kvq * 32 + 1) * 4096 + tid * 8;

  char* const rbuf = smem + 65536 + wid * 128;

  // prologue: stage tile 0 into buf 0
#pragma unroll
  for (int i = 0; i < 4; ++i) GLDS16(gsrc[i], smem + i * 8192 + tid * 16);

  f32x16 O[4];
#pragma unroll
  for (int dt = 0; dt < 4; ++dt)
#pragma unroll
    for (int j = 0; j < 16; ++j) O[dt][j] = 0.f;
  f32x16 zc;
#pragma unroll
  for (int j = 0; j < 16; ++j) zc[j] = 0.f;
  float mS = -3.0e38f, lS = 0.f;

  for (int t = 0; t < 16; ++t) {
    char* const b0 = smem + (t & 1) * 32768;
    if (t < 15) {
      char* const bn = smem + ((t + 1) & 1) * 32768;
      const size_t adv = (size_t)(t + 1) * 8192;
#pragma unroll
      for (int i = 0; i < 4; ++i) GLDS16(gsrc[i] + adv, bn + i * 8192 + tid * 16);
      asm volatile("s_waitcnt vmcnt(4)" ::: "memory");  // my tile-t slices landed
    } else {
      asm volatile("s_waitcnt vmcnt(0)" ::: "memory");
    }
    __builtin_amdgcn_s_barrier();                       // ALL tile-t slices in LDS
    __builtin_amdgcn_sched_barrier(0);

    // ---- QK^T swapped: two 32-kv subtiles, D[kv=regs][q=lane&31] ----
    f32x16 sT0, sT1;
    __builtin_amdgcn_s_setprio(1);
    {
      short8 kf[8];
#pragma unroll
      for (int kt = 0; kt < 8; ++kt)
        kf[kt] = *(const short8*)(b0 + kt * 1024 + lane * 16);
      sT0 = MFMA32(kf[0], qf[0], zc);
#pragma unroll
      for (int kt = 1; kt < 8; ++kt) sT0 = MFMA32(kf[kt], qf[kt], sT0);
    }
    {
      short8 kf[8];
#pragma unroll
      for (int kt = 0; kt < 8; ++kt)
        kf[kt] = *(const short8*)(b0 + 8192 + kt * 1024 + lane * 16);
      sT1 = MFMA32(kf[0], qf[0], zc);
#pragma unroll
      for (int kt = 1; kt < 8; ++kt) sT1 = MFMA32(kf[kt], qf[kt], sT1);
    }
    __builtin_amdgcn_s_setprio(0);

    // ---- online softmax over 64 kv; kv row of reg r = (r&3)+8*(r>>2)+4*hi --
    float pm = -3.0e38f;
#pragma unroll
    for (int r = 0; r < 16; ++r) pm = fmaxf(pm, fmaxf(sT0[r], sT1[r]));
    { i32x2 r = pls(iasi(pm), iasi(pm)); pm = fmaxf(fasf(r[0]), fasf(r[1])); }

    if (!__all(pm - mS <= 8.0f)) {          // defer-max (THR=8)
      float mnew = fmaxf(mS, pm);
      float fsc = exp2f((mS - mnew) * L2E);
      mS = mnew;
      lS *= fsc;
      if (hi == 0) *(float*)(rbuf + rr * 4) = fsc;
      f32x4 fr[4];
#pragma unroll
      for (int i = 0; i < 4; ++i)
        fr[i] = *(const f32x4*)(rbuf + i * 32 + hi * 16);
#pragma unroll
      for (int dt = 0; dt < 4; ++dt)
#pragma unroll
        for (int i = 0; i < 4; ++i)
#pragma unroll
          for (int j = 0; j < 4; ++j) O[dt][i * 4 + j] *= fr[i][j];
    }

    const float mL = mS * L2E;
    float pv0[16], pv1[16];
    float ts = 0.f;
#pragma unroll
    for (int r = 0; r < 16; ++r) {
      pv0[r] = exp2f(sT0[r] * L2E - mL);
      pv1[r] = exp2f(sT1[r] * L2E - mL);
      ts += pv0[r] + pv1[r];
    }
    { i32x2 r = pls(iasi(ts), iasi(ts)); ts = fasf(r[0]) + fasf(r[1]); }
    lS += ts;

    // ---- P -> PV A-fragments fully in registers (T12), 4 frags ----
    short8 pa[4];
    {
      int dw[8];
#pragma unroll
      for (int m = 0; m < 8; ++m) dw[m] = cvtpk(pv0[2 * m], pv0[2 * m + 1]);
      i32x2 ra = pls(dw[0], dw[2]);
      i32x2 rb = pls(dw[1], dw[3]);
      i32x2 rc = pls(dw[4], dw[6]);
      i32x2 rd = pls(dw[5], dw[7]);
      i32x4 w0 = {ra[0], rb[0], ra[1], rb[1]};
      i32x4 w1 = {rc[0], rd[0], rc[1], rd[1]};
      pa[0] = __builtin_bit_cast(short8, w0);
      pa[1] = __builtin_bit_cast(short8, w1);
    }
    {
      int dw[8];
#pragma unroll
      for (int m = 0; m < 8; ++m) dw[m] = cvtpk(pv1[2 * m], pv1[2 * m + 1]);
      i32x2 ra = pls(dw[0], dw[2]);
      i32x2 rb = pls(dw[1], dw[3]);
      i32x2 rc = pls(dw[4], dw[6]);
      i32x2 rd = pls(dw[5], dw[7]);
      i32x4 w0 = {ra[0], rb[0], ra[1], rb[1]};
      i32x4 w1 = {rc[0], rd[0], rc[1], rd[1]};
      pa[2] = __builtin_bit_cast(short8, w0);
      pa[3] = __builtin_bit_cast(short8, w1);
    }

    // ---- PV: O[q][d] += P[q][kv64] * V[kv64][d] ----
    __builtin_amdgcn_s_setprio(1);
#pragma unroll
    for (int ks = 0; ks < 4; ++ks) {
      const char* vb = b0 + 16384 + (ks >> 1) * 8192 + (ks & 1) * 4096;
      short8 vf[4];
#pragma unroll
      for (int dt = 0; dt < 4; ++dt)
        vf[dt] = *(const short8*)(vb + dt * 1024 + lane * 16);
#pragma unroll
      for (int dt = 0; dt < 4; ++dt) O[dt] = MFMA32(pa[ks], vf[dt], O[dt]);
    }
    __builtin_amdgcn_s_setprio(0);

    // trailing barrier: all waves done reading b0 -> free for restage at t+1
    __builtin_amdgcn_s_barrier();
  }

  // ---- epilogue: write partial A-frag image + (m,l); no LDS needed ----
  unsigned short* pab = PA + ((size_t)(b * 4 + kvq) * 128 + q0tile) * 4096;
#pragma unroll
  for (int dt = 0; dt < 4; ++dt) {
    int kt = dt * 2 + (rr >> 4);
#pragma unroll
    for (int r = 0; r < 16; ++r) {
      int q = (r & 3) + 8 * (r >> 2) + 4 * hi;
      int e = kt * 512 + (((rr >> 3) & 1) * 32 + q) * 8 + (rr & 7);
      pab[e] = f2bf(O[dt][r]);
    }
  }
  if (hi == 0)
    ML2[(size_t)(b * 4 + kvq) * 4096 + q0tile * 32 + rr] = make_float2(mS, lS);
}

// ---------------------------------------------------------------------------
// Kernel 3: merge 4 KV-quarter partials + fused output projection.
// Grid 512 = (4 b) x (128 q-tiles of 32); 256 thr = 4 waves; wave w -> out
// cols [w*32, w*32+32). Partial A-frag images are read directly as MFMA
// operands; per-lane (lane&31 = q row) c_h scaling merges them.
// ---------------------------------------------------------------------------
__global__ __launch_bounds__(256) void k_merge(
    const unsigned short* __restrict__ PA,
    const float2* __restrict__ ML2,
    const unsigned short* __restrict__ Wo2,
    const float* __restrict__ bo,
    float* __restrict__ out)
{
  const int tid = threadIdx.x, lane = tid & 63, w = tid >> 6;
  const int rr = lane & 31, hi = lane >> 5;
  const int p = blockIdx.x;
  const int b = p >> 7, qt32 = p & 127;

  // per-lane (q = rr) merge coefficients
  float mh[4], lh[4];
#pragma unroll
  for (int h = 0; h < 4; ++h) {
    float2 ml = ML2[(size_t)(b * 4 + h) * 4096 + qt32 * 32 + rr];
    mh[h] = ml.x; lh[h] = ml.y;
  }
  float M = fmaxf(fmaxf(mh[0], mh[1]), fmaxf(mh[2], mh[3]));
  float ch[4], L = 0.f;
#pragma unroll
  for (int h = 0; h < 4; ++h) { ch[h] = exp2f((mh[h] - M) * L2E); L += ch[h] * lh[h]; }
  float iL = 1.0f / L;
#pragma unroll
  for (int h = 0; h < 4; ++h) ch[h] *= iL;

  // merged att A-fragments (lane row = q = lane&31 -> ch is per-lane correct)
  short8 attb[8];
#pragma unroll
  for (int kt = 0; kt < 8; ++kt) {
    float a[8];
#pragma unroll
    for (int j = 0; j < 8; ++j) a[j] = 0.f;
#pragma unroll
    for (int h = 0; h < 4; ++h) {
      short8 ph = *(const short8*)(PA + ((size_t)(b * 4 + h) * 128 + qt32) * 4096 +
                                   kt * 512 + lane * 8);
#pragma unroll
      for (int j = 0; j < 8; ++j)
        a[j] += ch[h] * bf2f((unsigned short)ph[j]);
    }
    i32x4 wv = {cvtpk(a[0], a[1]), cvtpk(a[2], a[3]),
                cvtpk(a[4], a[5]), cvtpk(a[6], a[7])};
    attb[kt] = __builtin_bit_cast(short8, wv);
  }

  // out-proj col tile w
  short8 wof[8];
#pragma unroll
  for (int kt = 0; kt < 8; ++kt)
    wof[kt] = *(const short8*)(Wo2 + (w * 8 + kt) * 512 + lane * 8);

  f32x16 zc;
#pragma unroll
  for (int j = 0; j < 16; ++j) zc[j] = 0.f;
  f32x16 acc = MFMA32(attb[0], wof[0], zc);
#pragma unroll
  for (int kt = 1; kt < 8; ++kt) acc = MFMA32(attb[kt], wof[kt], acc);

  float bov = bo[w * 32 + rr];
  float* op = out + (size_t)(b * 4096 + qt32 * 32) * 128 + w * 32 + rr;
#pragma unroll
  for (int r = 0; r < 16; ++r) {
    int q = (r & 3) + 8 * (r >> 2) + 4 * hi;
    op[q * 128] = acc[r] + bov;
  }
}

// ---------------------------------------------------------------------------
extern "C" void kernel_launch(void* const* d_in, const int* in_sizes, int n_in,
                              void* d_out, int out_size, void* d_ws, size_t ws_size,
                              hipStream_t stream) {
  const float* x  = (const float*)d_in[0];
  const float* Wq = (const float*)d_in[1];
  const float* bq = (const float*)d_in[2];
  const float* Wk = (const float*)d_in[3];
  const float* bk = (const float*)d_in[4];
  const float* Wv = (const float*)d_in[5];
  const float* bv = (const float*)d_in[6];
  const float* Wo = (const float*)d_in[7];
  const float* bo = (const float*)d_in[8];

  const size_t NE = 4u * 4096u * 128u;       // 2M elems per tensor
  unsigned short* Q2  = (unsigned short*)d_ws;
  unsigned short* K2  = Q2 + NE;
  unsigned short* V2  = K2 + NE;
  unsigned short* Wo2 = V2 + NE;             // 16384 elems
  unsigned short* PA  = Wo2 + 16384;         // 16 * 128 * 4096 = 8M elems
  float2*         ML2 = (float2*)(PA + (size_t)16 * 128 * 4096);  // 64K float2

  k_proj<<<256, 256, 0, stream>>>(x, Wq, bq, Wk, bk, Wv, bv, Wo, Q2, K2, V2, Wo2);
  k_attn<<<256, 512, 0, stream>>>(Q2, K2, V2, PA, ML2);
  k_merge<<<512, 256, 0, stream>>>(PA, ML2, Wo2, bo, (float*)d_out);
}

// Round 13
// 91.358 us; speedup vs baseline: 1.4252x; 1.4252x over previous
//
#include <hip/hip_runtime.h>
#include <stdint.h>

typedef __attribute__((ext_vector_type(8))) short short8;
typedef __attribute__((ext_vector_type(4))) float f32x4;
typedef __attribute__((ext_vector_type(16))) float f32x16;
typedef __attribute__((ext_vector_type(4))) int i32x4;
typedef __attribute__((ext_vector_type(2))) int i32x2;

#define MFMA16(a, b, c) __builtin_amdgcn_mfma_f32_16x16x32_bf16((a), (b), (c), 0, 0, 0)
#define MFMA32(a, b, c) __builtin_amdgcn_mfma_f32_32x32x16_bf16((a), (b), (c), 0, 0, 0)

typedef __attribute__((address_space(1))) const void GVoid;
typedef __attribute__((address_space(3))) void LVoid;
#define GLDS16(g, l) __builtin_amdgcn_global_load_lds((GVoid*)(g), (LVoid*)(l), 16, 0, 0)

#define L2E 1.4426950408889634f

__device__ __forceinline__ unsigned short f2bf(float f) {
  unsigned int u = __builtin_bit_cast(unsigned int, f);
  u += 0x7fffu + ((u >> 16) & 1u);   // RNE (finite values only)
  return (unsigned short)(u >> 16);
}
__device__ __forceinline__ float bf2f(unsigned short u) {
  return __builtin_bit_cast(float, (unsigned int)u << 16);
}

// permlane32_swap via builtin: two simultaneously-live results -> distinct regs
// guaranteed (inline-asm "+v","+v" self-swap was R3's bug).
__device__ __forceinline__ i32x2 pls(int a, int b) {
  return __builtin_amdgcn_permlane32_swap(a, b, false, false);
}
__device__ __forceinline__ float fasf(int x) { return __builtin_bit_cast(float, x); }
__device__ __forceinline__ int iasi(float x) { return __builtin_bit_cast(int, x); }

__device__ __forceinline__ int cvtpk(float lo, float hi) {
  int d;
  asm("v_cvt_pk_bf16_f32 %0, %1, %2" : "=v"(d) : "v"(lo), "v"(hi));
  return d;
}

// ---------------------------------------------------------------------------
// Kernel 1: Q/K/V projections, written in MFMA-fragment-ready tiled layouts
// (32-row tiles):
//   Q2/K2: elem[(b*128 + tile)*4096 + kt*512 + ((h>>3)&1)*256 + (s&31)*8 + (h&7)]
//   V2:    elem[(b*128 + tile)*4096 + ((s>>4)&1)*2048 + (d>>5)*512
//               + ((s>>3)&1)*256 + (d&31)*8 + (s&7)]
//   Wo2:   elem[((oc>>5)*8 + (h>>4))*512 + ((h>>3)&1)*256 + (oc&31)*8 + (h&7)]
// Q pre-scaled by 1/sqrt(128). Q2/K2 written via LDS-transpose staging so all
// global stores are coalesced 16B chunks.
// ---------------------------------------------------------------------------
__global__ __launch_bounds__(256) void k_proj(
    const float* __restrict__ x,
    const float* __restrict__ Wq, const float* __restrict__ bq,
    const float* __restrict__ Wk, const float* __restrict__ bk,
    const float* __restrict__ Wv, const float* __restrict__ bv,
    const float* __restrict__ Wo,
    unsigned short* __restrict__ Q2, unsigned short* __restrict__ K2,
    unsigned short* __restrict__ V2, unsigned short* __restrict__ Wo2)
{
  __shared__ __align__(16) unsigned short wt[128 * 128];  // swizzled W^T, 32KB
  __shared__ __align__(16) unsigned short st[64 * 136];   // store-stage, 17KB
  const int tid  = threadIdx.x;
  const int lane = tid & 63;
  const int wid  = tid >> 6;
  const int l15  = lane & 15;
  const int g    = lane >> 4;
  const int r0   = blockIdx.x * 64 + wid * 16;

  if (blockIdx.x == 0) {
    for (int e = tid; e < 16384; e += 256) {
      int j = e & 7, ln = (e >> 3) & 63, kt = (e >> 9) & 7, dt = e >> 12;
      int h = kt * 16 + (ln >> 5) * 8 + j, oc = dt * 32 + (ln & 31);
      Wo2[e] = f2bf(Wo[h * 128 + oc]);
    }
  }

  short8 af[4];
  {
    const float* xp = x + (r0 + l15) * 128 + g * 8;
#pragma unroll
    for (int kt = 0; kt < 4; ++kt) {
      float4 v0 = *(const float4*)(xp + kt * 32);
      float4 v1 = *(const float4*)(xp + kt * 32 + 4);
      short8 a;
      a[0] = (short)f2bf(v0.x); a[1] = (short)f2bf(v0.y);
      a[2] = (short)f2bf(v0.z); a[3] = (short)f2bf(v0.w);
      a[4] = (short)f2bf(v1.x); a[5] = (short)f2bf(v1.y);
      a[6] = (short)f2bf(v1.z); a[7] = (short)f2bf(v1.w);
      af[kt] = a;
    }
  }

  const float* Ws[3] = {Wq, Wk, Wv};
  const float* bs[3] = {bq, bk, bv};

  for (int wI = 0; wI < 3; ++wI) {
    __syncthreads();
    const float* W = Ws[wI];
    for (int i = 0; i < 64; ++i) {
      int idx = i * 256 + tid;
      int k = idx >> 7, n = idx & 127;
      int cs = (k >> 3) ^ (n & 7);
      wt[n * 128 + cs * 8 + (k & 7)] = f2bf(W[idx]);
    }
    __syncthreads();

    float bias[8];
#pragma unroll
    for (int nt = 0; nt < 8; ++nt) bias[nt] = bs[wI][nt * 16 + l15];

    f32x4 acc[8];
#pragma unroll
    for (int nt = 0; nt < 8; ++nt) acc[nt] = (f32x4){0.f, 0.f, 0.f, 0.f};

#pragma unroll
    for (int nt = 0; nt < 8; ++nt) {
      const int n = nt * 16 + l15;
#pragma unroll
      for (int ks = 0; ks < 4; ++ks) {
        int cs = (ks * 4 + g) ^ (n & 7);
        short8 bf = *(const short8*)&wt[n * 128 + cs * 8];
        acc[nt] = MFMA16(af[ks], bf, acc[nt]);
      }
    }

    // D layout: col = nt*16 + l15 (h/d dim), row m = r0 + g*4 + r (s dim)
    if (wI < 2) {
      const float sc = (wI == 0) ? 0.08838834764831845f : 1.0f;  // 1/sqrt(128)
      // stage to padded LDS tile [64 rows][136 cols]
#pragma unroll
      for (int nt = 0; nt < 8; ++nt) {
        int col = nt * 16 + l15;
#pragma unroll
        for (int r = 0; r < 4; ++r)
          st[(wid * 16 + g * 4 + r) * 136 + col] = f2bf((acc[nt][r] + bias[nt]) * sc);
      }
      __syncthreads();
      // coalesced fragment-order writes: 1024 chunks of 16B, 4 per thread
      unsigned short* Og = (wI == 0) ? Q2 : K2;
#pragma unroll
      for (int c4 = 0; c4 < 4; ++c4) {
        int c = c4 * 256 + tid;
        int T = c >> 9, cc = c & 511;
        int kt = cc >> 6, hib = (cc >> 5) & 1, s32 = cc & 31;
        int m0 = blockIdx.x * 64 + T * 32;
        int bb = m0 >> 12, tile = (m0 & 4095) >> 5;
        short8 v = *(const short8*)&st[(T * 32 + s32) * 136 + kt * 16 + hib * 8];
        *(short8*)&Og[(size_t)(bb * 128 + tile) * 4096 + cc * 8] = v;
      }
    } else {
#pragma unroll
      for (int nt = 0; nt < 8; ++nt) {
        int col = nt * 16 + l15;
        int m0 = r0 + g * 4;
        int bb = m0 >> 12, srow = m0 & 4095;
        int idx = (bb * 128 + (srow >> 5)) * 4096 + ((srow >> 4) & 1) * 2048 +
                  (col >> 5) * 512 + ((srow >> 3) & 1) * 256 + (col & 31) * 8 +
                  (srow & 7);
        ushort4 pk;
        pk.x = f2bf(acc[nt][0] + bias[nt]);
        pk.y = f2bf(acc[nt][1] + bias[nt]);
        pk.z = f2bf(acc[nt][2] + bias[nt]);
        pk.w = f2bf(acc[nt][3] + bias[nt]);
        *(ushort4*)&V2[idx] = pk;
      }
    }
  }
}

// ---------------------------------------------------------------------------
// Kernel 2: flash attention partials, LDS-shared KV, split-KV over blocks.
// Grid 256 = (4 b) x (16 q-supertiles of 256 rows) x (4 KV quarters).
// 512 thr = 8 waves x 32 q-rows; KVBLK=64, 16 iters over the 1024-kv quarter.
// DOUBLE-buffered 32KB K+V tile (global_load_lds, 1-ahead prefetch, counted
// vmcnt(4)); two raw s_barriers per iter. 66.5KB LDS + ~88 VGPR ->
// 2 blocks/CU by HW occupancy. NOTE: launch_bounds min-waves arg must stay 2
// — R12's (512,4) capped VGPRs at 64 and spilled O[] to scratch (64MB
// WRITE_SIZE, 1.7x slowdown).
// Output: partial O as bf16 A-fragment image PA + (m,l) in ML2.
// ---------------------------------------------------------------------------
__global__ __launch_bounds__(512, 2) void k_attn(
    const unsigned short* __restrict__ Q2,
    const unsigned short* __restrict__ K2,
    const unsigned short* __restrict__ V2,
    unsigned short* __restrict__ PA,
    float2* __restrict__ ML2)
{
  __shared__ __align__(16) char smem[66560];   // 2 x 32KB bufs + 1KB RBUF
  const int tid = threadIdx.x, lane = tid & 63, wid = tid >> 6;
  const int rr = lane & 31, hi = lane >> 5;
  // XCD-aware: batch b pinned to XCD pair {2b,2b+1}
  const int p = blockIdx.x;
  const int b = (p & 7) >> 1;
  const int idx = ((p >> 3) << 1) | (p & 1);   // 0..63
  const int qt = idx >> 2, kvq = idx & 3;
  const int q0tile = qt * 8 + wid;             // 32q-tile index 0..127

  // Q fragments (pre-scaled): 8 coalesced 1KB loads
  short8 qf[8];
  {
    const unsigned short* qp = Q2 + (size_t)(b * 128 + q0tile) * 4096 + lane * 8;
#pragma unroll
    for (int kt = 0; kt < 8; ++kt) qf[kt] = *(const short8*)(qp + kt * 512);
  }

  // staging sources: thread tid stages 4 x 16B chunks -> K tile0/1, V tile0/1
  const unsigned short* gsrc[4];
  gsrc[0] = K2 + (size_t)(b * 128 + kvq * 32 + 0) * 4096 + tid * 8;
  gsrc[1] = K2 + (size_t)(b * 128 + kvq * 32 + 1) * 4096 + tid * 8;
  gsrc[2] = V2 + (size_t)(b * 128 + kvq * 32 + 0) * 4096 + tid * 8;
  gsrc[3] = V2 + (size_t)(b * 128 + kvq * 32 + 1) * 4096 + tid * 8;

  char* const rbuf = smem + 65536 + wid * 128;

  // prologue: stage tile 0 into buf 0
#pragma unroll
  for (int i = 0; i < 4; ++i) GLDS16(gsrc[i], smem + i * 8192 + tid * 16);

  f32x16 O[4];
#pragma unroll
  for (int dt = 0; dt < 4; ++dt)
#pragma unroll
    for (int j = 0; j < 16; ++j) O[dt][j] = 0.f;
  f32x16 zc;
#pragma unroll
  for (int j = 0; j < 16; ++j) zc[j] = 0.f;
  float mS = -3.0e38f, lS = 0.f;

  for (int t = 0; t < 16; ++t) {
    char* const b0 = smem + (t & 1) * 32768;
    if (t < 15) {
      char* const bn = smem + ((t + 1) & 1) * 32768;
      const size_t adv = (size_t)(t + 1) * 8192;
#pragma unroll
      for (int i = 0; i < 4; ++i) GLDS16(gsrc[i] + adv, bn + i * 8192 + tid * 16);
      asm volatile("s_waitcnt vmcnt(4)" ::: "memory");  // my tile-t slices landed
    } else {
      asm volatile("s_waitcnt vmcnt(0)" ::: "memory");
    }
    __builtin_amdgcn_s_barrier();                       // ALL tile-t slices in LDS
    __builtin_amdgcn_sched_barrier(0);

    // ---- QK^T swapped: two 32-kv subtiles, D[kv=regs][q=lane&31] ----
    f32x16 sT0, sT1;
    __builtin_amdgcn_s_setprio(1);
    {
      short8 kf[8];
#pragma unroll
      for (int kt = 0; kt < 8; ++kt)
        kf[kt] = *(const short8*)(b0 + kt * 1024 + lane * 16);
      sT0 = MFMA32(kf[0], qf[0], zc);
#pragma unroll
      for (int kt = 1; kt < 8; ++kt) sT0 = MFMA32(kf[kt], qf[kt], sT0);
    }
    {
      short8 kf[8];
#pragma unroll
      for (int kt = 0; kt < 8; ++kt)
        kf[kt] = *(const short8*)(b0 + 8192 + kt * 1024 + lane * 16);
      sT1 = MFMA32(kf[0], qf[0], zc);
#pragma unroll
      for (int kt = 1; kt < 8; ++kt) sT1 = MFMA32(kf[kt], qf[kt], sT1);
    }
    __builtin_amdgcn_s_setprio(0);

    // ---- online softmax over 64 kv; kv row of reg r = (r&3)+8*(r>>2)+4*hi --
    float pm = -3.0e38f;
#pragma unroll
    for (int r = 0; r < 16; ++r) pm = fmaxf(pm, fmaxf(sT0[r], sT1[r]));
    { i32x2 r = pls(iasi(pm), iasi(pm)); pm = fmaxf(fasf(r[0]), fasf(r[1])); }

    if (!__all(pm - mS <= 8.0f)) {          // defer-max (THR=8)
      float mnew = fmaxf(mS, pm);
      float fsc = exp2f((mS - mnew) * L2E);
      mS = mnew;
      lS *= fsc;
      if (hi == 0) *(float*)(rbuf + rr * 4) = fsc;
      f32x4 fr[4];
#pragma unroll
      for (int i = 0; i < 4; ++i)
        fr[i] = *(const f32x4*)(rbuf + i * 32 + hi * 16);
#pragma unroll
      for (int dt = 0; dt < 4; ++dt)
#pragma unroll
        for (int i = 0; i < 4; ++i)
#pragma unroll
          for (int j = 0; j < 4; ++j) O[dt][i * 4 + j] *= fr[i][j];
    }

    const float mL = mS * L2E;
    float pv0[16], pv1[16];
    float ts = 0.f;
#pragma unroll
    for (int r = 0; r < 16; ++r) {
      pv0[r] = exp2f(sT0[r] * L2E - mL);
      pv1[r] = exp2f(sT1[r] * L2E - mL);
      ts += pv0[r] + pv1[r];
    }
    { i32x2 r = pls(iasi(ts), iasi(ts)); ts = fasf(r[0]) + fasf(r[1]); }
    lS += ts;

    // ---- P -> PV A-fragments fully in registers (T12), 4 frags ----
    short8 pa[4];
    {
      int dw[8];
#pragma unroll
      for (int m = 0; m < 8; ++m) dw[m] = cvtpk(pv0[2 * m], pv0[2 * m + 1]);
      i32x2 ra = pls(dw[0], dw[2]);
      i32x2 rb = pls(dw[1], dw[3]);
      i32x2 rc = pls(dw[4], dw[6]);
      i32x2 rd = pls(dw[5], dw[7]);
      i32x4 w0 = {ra[0], rb[0], ra[1], rb[1]};
      i32x4 w1 = {rc[0], rd[0], rc[1], rd[1]};
      pa[0] = __builtin_bit_cast(short8, w0);
      pa[1] = __builtin_bit_cast(short8, w1);
    }
    {
      int dw[8];
#pragma unroll
      for (int m = 0; m < 8; ++m) dw[m] = cvtpk(pv1[2 * m], pv1[2 * m + 1]);
      i32x2 ra = pls(dw[0], dw[2]);
      i32x2 rb = pls(dw[1], dw[3]);
      i32x2 rc = pls(dw[4], dw[6]);
      i32x2 rd = pls(dw[5], dw[7]);
      i32x4 w0 = {ra[0], rb[0], ra[1], rb[1]};
      i32x4 w1 = {rc[0], rd[0], rc[1], rd[1]};
      pa[2] = __builtin_bit_cast(short8, w0);
      pa[3] = __builtin_bit_cast(short8, w1);
    }

    // ---- PV: O[q][d] += P[q][kv64] * V[kv64][d] ----
    __builtin_amdgcn_s_setprio(1);
#pragma unroll
    for (int ks = 0; ks < 4; ++ks) {
      const char* vb = b0 + 16384 + (ks >> 1) * 8192 + (ks & 1) * 4096;
      short8 vf[4];
#pragma unroll
      for (int dt = 0; dt < 4; ++dt)
        vf[dt] = *(const short8*)(vb + dt * 1024 + lane * 16);
#pragma unroll
      for (int dt = 0; dt < 4; ++dt) O[dt] = MFMA32(pa[ks], vf[dt], O[dt]);
    }
    __builtin_amdgcn_s_setprio(0);

    // trailing barrier: all waves done reading b0 -> free for restage at t+1
    __builtin_amdgcn_s_barrier();
  }

  // ---- epilogue: write partial A-frag image + (m,l); no LDS needed ----
  unsigned short* pab = PA + ((size_t)(b * 4 + kvq) * 128 + q0tile) * 4096;
#pragma unroll
  for (int dt = 0; dt < 4; ++dt) {
    int kt = dt * 2 + (rr >> 4);
#pragma unroll
    for (int r = 0; r < 16; ++r) {
      int q = (r & 3) + 8 * (r >> 2) + 4 * hi;
      int e = kt * 512 + (((rr >> 3) & 1) * 32 + q) * 8 + (rr & 7);
      pab[e] = f2bf(O[dt][r]);
    }
  }
  if (hi == 0)
    ML2[(size_t)(b * 4 + kvq) * 4096 + q0tile * 32 + rr] = make_float2(mS, lS);
}

// ---------------------------------------------------------------------------
// Kernel 3: merge 4 KV-quarter partials + fused output projection.
// Grid 512 = (4 b) x (128 q-tiles of 32); 256 thr = 4 waves; wave w -> out
// cols [w*32, w*32+32). Partial A-frag images are read directly as MFMA
// operands; per-lane (lane&31 = q row) c_h scaling merges them.
// ---------------------------------------------------------------------------
__global__ __launch_bounds__(256) void k_merge(
    const unsigned short* __restrict__ PA,
    const float2* __restrict__ ML2,
    const unsigned short* __restrict__ Wo2,
    const float* __restrict__ bo,
    float* __restrict__ out)
{
  const int tid = threadIdx.x, lane = tid & 63, w = tid >> 6;
  const int rr = lane & 31, hi = lane >> 5;
  const int p = blockIdx.x;
  const int b = p >> 7, qt32 = p & 127;

  // per-lane (q = rr) merge coefficients
  float mh[4], lh[4];
#pragma unroll
  for (int h = 0; h < 4; ++h) {
    float2 ml = ML2[(size_t)(b * 4 + h) * 4096 + qt32 * 32 + rr];
    mh[h] = ml.x; lh[h] = ml.y;
  }
  float M = fmaxf(fmaxf(mh[0], mh[1]), fmaxf(mh[2], mh[3]));
  float ch[4], L = 0.f;
#pragma unroll
  for (int h = 0; h < 4; ++h) { ch[h] = exp2f((mh[h] - M) * L2E); L += ch[h] * lh[h]; }
  float iL = 1.0f / L;
#pragma unroll
  for (int h = 0; h < 4; ++h) ch[h] *= iL;

  // merged att A-fragments (lane row = q = lane&31 -> ch is per-lane correct)
  short8 attb[8];
#pragma unroll
  for (int kt = 0; kt < 8; ++kt) {
    float a[8];
#pragma unroll
    for (int j = 0; j < 8; ++j) a[j] = 0.f;
#pragma unroll
    for (int h = 0; h < 4; ++h) {
      short8 ph = *(const short8*)(PA + ((size_t)(b * 4 + h) * 128 + qt32) * 4096 +
                                   kt * 512 + lane * 8);
#pragma unroll
      for (int j = 0; j < 8; ++j)
        a[j] += ch[h] * bf2f((unsigned short)ph[j]);
    }
    i32x4 wv = {cvtpk(a[0], a[1]), cvtpk(a[2], a[3]),
                cvtpk(a[4], a[5]), cvtpk(a[6], a[7])};
    attb[kt] = __builtin_bit_cast(short8, wv);
  }

  // out-proj col tile w
  short8 wof[8];
#pragma unroll
  for (int kt = 0; kt < 8; ++kt)
    wof[kt] = *(const short8*)(Wo2 + (w * 8 + kt) * 512 + lane * 8);

  f32x16 zc;
#pragma unroll
  for (int j = 0; j < 16; ++j) zc[j] = 0.f;
  f32x16 acc = MFMA32(attb[0], wof[0], zc);
#pragma unroll
  for (int kt = 1; kt < 8; ++kt) acc = MFMA32(attb[kt], wof[kt], acc);

  float bov = bo[w * 32 + rr];
  float* op = out + (size_t)(b * 4096 + qt32 * 32) * 128 + w * 32 + rr;
#pragma unroll
  for (int r = 0; r < 16; ++r) {
    int q = (r & 3) + 8 * (r >> 2) + 4 * hi;
    op[q * 128] = acc[r] + bov;
  }
}

// ---------------------------------------------------------------------------
extern "C" void kernel_launch(void* const* d_in, const int* in_sizes, int n_in,
                              void* d_out, int out_size, void* d_ws, size_t ws_size,
                              hipStream_t stream) {
  const float* x  = (const float*)d_in[0];
  const float* Wq = (const float*)d_in[1];
  const float* bq = (const float*)d_in[2];
  const float* Wk = (const float*)d_in[3];
  const float* bk = (const float*)d_in[4];
  const float* Wv = (const float*)d_in[5];
  const float* bv = (const float*)d_in[6];
  const float* Wo = (const float*)d_in[7];
  const float* bo = (const float*)d_in[8];

  const size_t NE = 4u * 4096u * 128u;       // 2M elems per tensor
  unsigned short* Q2  = (unsigned short*)d_ws;
  unsigned short* K2  = Q2 + NE;
  unsigned short* V2  = K2 + NE;
  unsigned short* Wo2 = V2 + NE;             // 16384 elems
  unsigned short* PA  = Wo2 + 16384;         // 16 * 128 * 4096 = 8M elems
  float2*         ML2 = (float2*)(PA + (size_t)16 * 128 * 4096);  // 64K float2

  k_proj<<<256, 256, 0, stream>>>(x, Wq, bq, Wk, bk, Wv, bv, Wo, Q2, K2, V2, Wo2);
  k_attn<<<256, 512, 0, stream>>>(Q2, K2, V2, PA, ML2);
  k_merge<<<512, 256, 0, stream>>>(PA, ML2, Wo2, bo, (float*)d_out);
}

// Round 14
// 88.581 us; speedup vs baseline: 1.4699x; 1.0313x over previous
//
#include <hip/hip_runtime.h>
#include <stdint.h>

typedef __attribute__((ext_vector_type(8))) short short8;
typedef __attribute__((ext_vector_type(4))) float f32x4;
typedef __attribute__((ext_vector_type(16))) float f32x16;
typedef __attribute__((ext_vector_type(4))) int i32x4;
typedef __attribute__((ext_vector_type(2))) int i32x2;

#define MFMA16(a, b, c) __builtin_amdgcn_mfma_f32_16x16x32_bf16((a), (b), (c), 0, 0, 0)
#define MFMA32(a, b, c) __builtin_amdgcn_mfma_f32_32x32x16_bf16((a), (b), (c), 0, 0, 0)

typedef __attribute__((address_space(1))) const void GVoid;
typedef __attribute__((address_space(3))) void LVoid;
#define GLDS16(g, l) __builtin_amdgcn_global_load_lds((GVoid*)(g), (LVoid*)(l), 16, 0, 0)

#define L2E 1.4426950408889634f

__device__ __forceinline__ unsigned short f2bf(float f) {
  unsigned int u = __builtin_bit_cast(unsigned int, f);
  u += 0x7fffu + ((u >> 16) & 1u);   // RNE (finite values only)
  return (unsigned short)(u >> 16);
}
__device__ __forceinline__ float bf2f(unsigned short u) {
  return __builtin_bit_cast(float, (unsigned int)u << 16);
}

// permlane32_swap via builtin: two simultaneously-live results -> distinct regs
// guaranteed (inline-asm "+v","+v" self-swap was R3's bug).
__device__ __forceinline__ i32x2 pls(int a, int b) {
  return __builtin_amdgcn_permlane32_swap(a, b, false, false);
}
__device__ __forceinline__ float fasf(int x) { return __builtin_bit_cast(float, x); }
__device__ __forceinline__ int iasi(float x) { return __builtin_bit_cast(int, x); }

__device__ __forceinline__ int cvtpk(float lo, float hi) {
  int d;
  asm("v_cvt_pk_bf16_f32 %0, %1, %2" : "=v"(d) : "v"(lo), "v"(hi));
  return d;
}

// ---------------------------------------------------------------------------
// Kernel 1: Q/K/V projections, written in MFMA-fragment-ready tiled layouts
// (32-row tiles):
//   Q2/K2: elem[(b*128 + tile)*4096 + kt*512 + ((h>>3)&1)*256 + (s&31)*8 + (h&7)]
//   V2:    elem[(b*128 + tile)*4096 + ((s>>4)&1)*2048 + (d>>5)*512
//               + ((s>>3)&1)*256 + (d&31)*8 + (s&7)]
//   Wo2:   elem[((oc>>5)*8 + (h>>4))*512 + ((h>>3)&1)*256 + (oc&31)*8 + (h&7)]
// Q pre-scaled by 1/sqrt(128). Q2/K2 written via LDS-transpose staging so all
// global stores are coalesced 16B chunks.
// ---------------------------------------------------------------------------
__global__ __launch_bounds__(256) void k_proj(
    const float* __restrict__ x,
    const float* __restrict__ Wq, const float* __restrict__ bq,
    const float* __restrict__ Wk, const float* __restrict__ bk,
    const float* __restrict__ Wv, const float* __restrict__ bv,
    const float* __restrict__ Wo,
    unsigned short* __restrict__ Q2, unsigned short* __restrict__ K2,
    unsigned short* __restrict__ V2, unsigned short* __restrict__ Wo2)
{
  __shared__ __align__(16) unsigned short wt[128 * 128];  // swizzled W^T, 32KB
  __shared__ __align__(16) unsigned short st[64 * 136];   // store-stage, 17KB
  const int tid  = threadIdx.x;
  const int lane = tid & 63;
  const int wid  = tid >> 6;
  const int l15  = lane & 15;
  const int g    = lane >> 4;
  const int r0   = blockIdx.x * 64 + wid * 16;

  if (blockIdx.x == 0) {
    for (int e = tid; e < 16384; e += 256) {
      int j = e & 7, ln = (e >> 3) & 63, kt = (e >> 9) & 7, dt = e >> 12;
      int h = kt * 16 + (ln >> 5) * 8 + j, oc = dt * 32 + (ln & 31);
      Wo2[e] = f2bf(Wo[h * 128 + oc]);
    }
  }

  short8 af[4];
  {
    const float* xp = x + (r0 + l15) * 128 + g * 8;
#pragma unroll
    for (int kt = 0; kt < 4; ++kt) {
      float4 v0 = *(const float4*)(xp + kt * 32);
      float4 v1 = *(const float4*)(xp + kt * 32 + 4);
      short8 a;
      a[0] = (short)f2bf(v0.x); a[1] = (short)f2bf(v0.y);
      a[2] = (short)f2bf(v0.z); a[3] = (short)f2bf(v0.w);
      a[4] = (short)f2bf(v1.x); a[5] = (short)f2bf(v1.y);
      a[6] = (short)f2bf(v1.z); a[7] = (short)f2bf(v1.w);
      af[kt] = a;
    }
  }

  const float* Ws[3] = {Wq, Wk, Wv};
  const float* bs[3] = {bq, bk, bv};

  for (int wI = 0; wI < 3; ++wI) {
    __syncthreads();
    const float* W = Ws[wI];
    for (int i = 0; i < 64; ++i) {
      int idx = i * 256 + tid;
      int k = idx >> 7, n = idx & 127;
      int cs = (k >> 3) ^ (n & 7);
      wt[n * 128 + cs * 8 + (k & 7)] = f2bf(W[idx]);
    }
    __syncthreads();

    float bias[8];
#pragma unroll
    for (int nt = 0; nt < 8; ++nt) bias[nt] = bs[wI][nt * 16 + l15];

    f32x4 acc[8];
#pragma unroll
    for (int nt = 0; nt < 8; ++nt) acc[nt] = (f32x4){0.f, 0.f, 0.f, 0.f};

#pragma unroll
    for (int nt = 0; nt < 8; ++nt) {
      const int n = nt * 16 + l15;
#pragma unroll
      for (int ks = 0; ks < 4; ++ks) {
        int cs = (ks * 4 + g) ^ (n & 7);
        short8 bf = *(const short8*)&wt[n * 128 + cs * 8];
        acc[nt] = MFMA16(af[ks], bf, acc[nt]);
      }
    }

    // D layout: col = nt*16 + l15 (h/d dim), row m = r0 + g*4 + r (s dim)
    if (wI < 2) {
      const float sc = (wI == 0) ? 0.08838834764831845f : 1.0f;  // 1/sqrt(128)
      // stage to padded LDS tile [64 rows][136 cols]
#pragma unroll
      for (int nt = 0; nt < 8; ++nt) {
        int col = nt * 16 + l15;
#pragma unroll
        for (int r = 0; r < 4; ++r)
          st[(wid * 16 + g * 4 + r) * 136 + col] = f2bf((acc[nt][r] + bias[nt]) * sc);
      }
      __syncthreads();
      // coalesced fragment-order writes: 1024 chunks of 16B, 4 per thread
      unsigned short* Og = (wI == 0) ? Q2 : K2;
#pragma unroll
      for (int c4 = 0; c4 < 4; ++c4) {
        int c = c4 * 256 + tid;
        int T = c >> 9, cc = c & 511;
        int kt = cc >> 6, hib = (cc >> 5) & 1, s32 = cc & 31;
        int m0 = blockIdx.x * 64 + T * 32;
        int bb = m0 >> 12, tile = (m0 & 4095) >> 5;
        short8 v = *(const short8*)&st[(T * 32 + s32) * 136 + kt * 16 + hib * 8];
        *(short8*)&Og[(size_t)(bb * 128 + tile) * 4096 + cc * 8] = v;
      }
    } else {
#pragma unroll
      for (int nt = 0; nt < 8; ++nt) {
        int col = nt * 16 + l15;
        int m0 = r0 + g * 4;
        int bb = m0 >> 12, srow = m0 & 4095;
        int idx = (bb * 128 + (srow >> 5)) * 4096 + ((srow >> 4) & 1) * 2048 +
                  (col >> 5) * 512 + ((srow >> 3) & 1) * 256 + (col & 31) * 8 +
                  (srow & 7);
        ushort4 pk;
        pk.x = f2bf(acc[nt][0] + bias[nt]);
        pk.y = f2bf(acc[nt][1] + bias[nt]);
        pk.z = f2bf(acc[nt][2] + bias[nt]);
        pk.w = f2bf(acc[nt][3] + bias[nt]);
        *(ushort4*)&V2[idx] = pk;
      }
    }
  }
}

// ---------------------------------------------------------------------------
// Kernel 2: flash attention partials, LDS-shared KV, split-KV over blocks.
// Grid 512 = (4 b) x (32 q-supertiles of 128 rows) x (4 KV quarters);
// 256 thr = 4 waves x 32 q-rows -> TWO independent blocks per CU (the R13
// lesson: grid 256 on 256 CUs = 1 block/CU no matter the resources; a single
// barrier-coupled block exposes every vmcnt/barrier stall. Two blocks give
// independent barrier domains that overlap each other's stalls).
// KVBLK=64, 16 iters; double-buffered 32KB K+V tile (global_load_lds, 8 per
// thread, counted vmcnt(8)); two raw s_barriers per iter. LDS 65.5KB x 2
// blocks = 131KB/CU; VGPR ~84 -> 8 waves/CU.
// Output: partial O as bf16 A-fragment image PA + (m,l) in ML2 (16 sets,
// unchanged from R13 -> merge kernel identical).
// ---------------------------------------------------------------------------
__global__ __launch_bounds__(256, 2) void k_attn(
    const unsigned short* __restrict__ Q2,
    const unsigned short* __restrict__ K2,
    const unsigned short* __restrict__ V2,
    unsigned short* __restrict__ PA,
    float2* __restrict__ ML2)
{
  __shared__ __align__(16) char smem[66560];   // 2 x 32KB bufs + 1KB RBUF
  const int tid = threadIdx.x, lane = tid & 63, wid = tid >> 6;   // wid 0..3
  const int rr = lane & 31, hi = lane >> 5;
  // XCD-aware: batch b pinned to XCD pair {2b,2b+1}
  const int p = blockIdx.x;
  const int b = (p & 7) >> 1;
  const int idx = ((p >> 3) << 1) | (p & 1);   // 0..127
  const int qst = idx >> 2, kvq = idx & 3;     // qst 0..31
  const int q0tile = qst * 4 + wid;            // 32q-tile index 0..127

  // Q fragments (pre-scaled): 8 coalesced 1KB loads
  short8 qf[8];
  {
    const unsigned short* qp = Q2 + (size_t)(b * 128 + q0tile) * 4096 + lane * 8;
#pragma unroll
    for (int kt = 0; kt < 8; ++kt) qf[kt] = *(const short8*)(qp + kt * 512);
  }

  // staging sources: thread tid stages 8 x 16B chunks (2 per 8KB tile)
  const unsigned short* gsrc[4];
  gsrc[0] = K2 + (size_t)(b * 128 + kvq * 32 + 0) * 4096 + tid * 8;
  gsrc[1] = K2 + (size_t)(b * 128 + kvq * 32 + 1) * 4096 + tid * 8;
  gsrc[2] = V2 + (size_t)(b * 128 + kvq * 32 + 0) * 4096 + tid * 8;
  gsrc[3] = V2 + (size_t)(b * 128 + kvq * 32 + 1) * 4096 + tid * 8;

  char* const rbuf = smem + 65536 + wid * 128;

  // prologue: stage tile 0 into buf 0
#pragma unroll
  for (int i = 0; i < 4; ++i) {
    GLDS16(gsrc[i], smem + i * 8192 + tid * 16);
    GLDS16(gsrc[i] + 2048, smem + i * 8192 + 4096 + tid * 16);
  }

  f32x16 O[4];
#pragma unroll
  for (int dt = 0; dt < 4; ++dt)
#pragma unroll
    for (int j = 0; j < 16; ++j) O[dt][j] = 0.f;
  f32x16 zc;
#pragma unroll
  for (int j = 0; j < 16; ++j) zc[j] = 0.f;
  float mS = -3.0e38f, lS = 0.f;

  for (int t = 0; t < 16; ++t) {
    char* const b0 = smem + (t & 1) * 32768;
    if (t < 15) {
      char* const bn = smem + ((t + 1) & 1) * 32768;
      const size_t adv = (size_t)(t + 1) * 8192;
#pragma unroll
      for (int i = 0; i < 4; ++i) {
        GLDS16(gsrc[i] + adv, bn + i * 8192 + tid * 16);
        GLDS16(gsrc[i] + adv + 2048, bn + i * 8192 + 4096 + tid * 16);
      }
      asm volatile("s_waitcnt vmcnt(8)" ::: "memory");  // my tile-t slices landed
    } else {
      asm volatile("s_waitcnt vmcnt(0)" ::: "memory");
    }
    __builtin_amdgcn_s_barrier();                       // ALL tile-t slices in LDS
    __builtin_amdgcn_sched_barrier(0);

    // ---- QK^T swapped: two 32-kv subtiles, D[kv=regs][q=lane&31] ----
    f32x16 sT0, sT1;
    __builtin_amdgcn_s_setprio(1);
    {
      short8 kf[8];
#pragma unroll
      for (int kt = 0; kt < 8; ++kt)
        kf[kt] = *(const short8*)(b0 + kt * 1024 + lane * 16);
      sT0 = MFMA32(kf[0], qf[0], zc);
#pragma unroll
      for (int kt = 1; kt < 8; ++kt) sT0 = MFMA32(kf[kt], qf[kt], sT0);
    }
    {
      short8 kf[8];
#pragma unroll
      for (int kt = 0; kt < 8; ++kt)
        kf[kt] = *(const short8*)(b0 + 8192 + kt * 1024 + lane * 16);
      sT1 = MFMA32(kf[0], qf[0], zc);
#pragma unroll
      for (int kt = 1; kt < 8; ++kt) sT1 = MFMA32(kf[kt], qf[kt], sT1);
    }
    __builtin_amdgcn_s_setprio(0);

    // ---- online softmax over 64 kv; kv row of reg r = (r&3)+8*(r>>2)+4*hi --
    float pm = -3.0e38f;
#pragma unroll
    for (int r = 0; r < 16; ++r) pm = fmaxf(pm, fmaxf(sT0[r], sT1[r]));
    { i32x2 r = pls(iasi(pm), iasi(pm)); pm = fmaxf(fasf(r[0]), fasf(r[1])); }

    if (!__all(pm - mS <= 8.0f)) {          // defer-max (THR=8)
      float mnew = fmaxf(mS, pm);
      float fsc = exp2f((mS - mnew) * L2E);
      mS = mnew;
      lS *= fsc;
      if (hi == 0) *(float*)(rbuf + rr * 4) = fsc;
      f32x4 fr[4];
#pragma unroll
      for (int i = 0; i < 4; ++i)
        fr[i] = *(const f32x4*)(rbuf + i * 32 + hi * 16);
#pragma unroll
      for (int dt = 0; dt < 4; ++dt)
#pragma unroll
        for (int i = 0; i < 4; ++i)
#pragma unroll
          for (int j = 0; j < 4; ++j) O[dt][i * 4 + j] *= fr[i][j];
    }

    const float mL = mS * L2E;
    float pv0[16], pv1[16];
    float ts = 0.f;
#pragma unroll
    for (int r = 0; r < 16; ++r) {
      pv0[r] = exp2f(sT0[r] * L2E - mL);
      pv1[r] = exp2f(sT1[r] * L2E - mL);
      ts += pv0[r] + pv1[r];
    }
    { i32x2 r = pls(iasi(ts), iasi(ts)); ts = fasf(r[0]) + fasf(r[1]); }
    lS += ts;

    // ---- P -> PV A-fragments fully in registers (T12), 4 frags ----
    short8 pa[4];
    {
      int dw[8];
#pragma unroll
      for (int m = 0; m < 8; ++m) dw[m] = cvtpk(pv0[2 * m], pv0[2 * m + 1]);
      i32x2 ra = pls(dw[0], dw[2]);
      i32x2 rb = pls(dw[1], dw[3]);
      i32x2 rc = pls(dw[4], dw[6]);
      i32x2 rd = pls(dw[5], dw[7]);
      i32x4 w0 = {ra[0], rb[0], ra[1], rb[1]};
      i32x4 w1 = {rc[0], rd[0], rc[1], rd[1]};
      pa[0] = __builtin_bit_cast(short8, w0);
      pa[1] = __builtin_bit_cast(short8, w1);
    }
    {
      int dw[8];
#pragma unroll
      for (int m = 0; m < 8; ++m) dw[m] = cvtpk(pv1[2 * m], pv1[2 * m + 1]);
      i32x2 ra = pls(dw[0], dw[2]);
      i32x2 rb = pls(dw[1], dw[3]);
      i32x2 rc = pls(dw[4], dw[6]);
      i32x2 rd = pls(dw[5], dw[7]);
      i32x4 w0 = {ra[0], rb[0], ra[1], rb[1]};
      i32x4 w1 = {rc[0], rd[0], rc[1], rd[1]};
      pa[2] = __builtin_bit_cast(short8, w0);
      pa[3] = __builtin_bit_cast(short8, w1);
    }

    // ---- PV: O[q][d] += P[q][kv64] * V[kv64][d] ----
    __builtin_amdgcn_s_setprio(1);
#pragma unroll
    for (int ks = 0; ks < 4; ++ks) {
      const char* vb = b0 + 16384 + (ks >> 1) * 8192 + (ks & 1) * 4096;
      short8 vf[4];
#pragma unroll
      for (int dt = 0; dt < 4; ++dt)
        vf[dt] = *(const short8*)(vb + dt * 1024 + lane * 16);
#pragma unroll
      for (int dt = 0; dt < 4; ++dt) O[dt] = MFMA32(pa[ks], vf[dt], O[dt]);
    }
    __builtin_amdgcn_s_setprio(0);

    // trailing barrier: all waves done reading b0 -> free for restage at t+1
    __builtin_amdgcn_s_barrier();
  }

  // ---- epilogue: write partial A-frag image + (m,l); no LDS needed ----
  unsigned short* pab = PA + ((size_t)(b * 4 + kvq) * 128 + q0tile) * 4096;
#pragma unroll
  for (int dt = 0; dt < 4; ++dt) {
    int kt = dt * 2 + (rr >> 4);
#pragma unroll
    for (int r = 0; r < 16; ++r) {
      int q = (r & 3) + 8 * (r >> 2) + 4 * hi;
      int e = kt * 512 + (((rr >> 3) & 1) * 32 + q) * 8 + (rr & 7);
      pab[e] = f2bf(O[dt][r]);
    }
  }
  if (hi == 0)
    ML2[(size_t)(b * 4 + kvq) * 4096 + q0tile * 32 + rr] = make_float2(mS, lS);
}

// ---------------------------------------------------------------------------
// Kernel 3: merge 4 KV-quarter partials + fused output projection.
// Grid 512 = (4 b) x (128 q-tiles of 32); 256 thr = 4 waves; wave w -> out
// cols [w*32, w*32+32). Partial A-frag images are read directly as MFMA
// operands; per-lane (lane&31 = q row) c_h scaling merges them.
// ---------------------------------------------------------------------------
__global__ __launch_bounds__(256) void k_merge(
    const unsigned short* __restrict__ PA,
    const float2* __restrict__ ML2,
    const unsigned short* __restrict__ Wo2,
    const float* __restrict__ bo,
    float* __restrict__ out)
{
  const int tid = threadIdx.x, lane = tid & 63, w = tid >> 6;
  const int rr = lane & 31, hi = lane >> 5;
  const int p = blockIdx.x;
  const int b = p >> 7, qt32 = p & 127;

  // per-lane (q = rr) merge coefficients
  float mh[4], lh[4];
#pragma unroll
  for (int h = 0; h < 4; ++h) {
    float2 ml = ML2[(size_t)(b * 4 + h) * 4096 + qt32 * 32 + rr];
    mh[h] = ml.x; lh[h] = ml.y;
  }
  float M = fmaxf(fmaxf(mh[0], mh[1]), fmaxf(mh[2], mh[3]));
  float ch[4], L = 0.f;
#pragma unroll
  for (int h = 0; h < 4; ++h) { ch[h] = exp2f((mh[h] - M) * L2E); L += ch[h] * lh[h]; }
  float iL = 1.0f / L;
#pragma unroll
  for (int h = 0; h < 4; ++h) ch[h] *= iL;

  // merged att A-fragments (lane row = q = lane&31 -> ch is per-lane correct)
  short8 attb[8];
#pragma unroll
  for (int kt = 0; kt < 8; ++kt) {
    float a[8];
#pragma unroll
    for (int j = 0; j < 8; ++j) a[j] = 0.f;
#pragma unroll
    for (int h = 0; h < 4; ++h) {
      short8 ph = *(const short8*)(PA + ((size_t)(b * 4 + h) * 128 + qt32) * 4096 +
                                   kt * 512 + lane * 8);
#pragma unroll
      for (int j = 0; j < 8; ++j)
        a[j] += ch[h] * bf2f((unsigned short)ph[j]);
    }
    i32x4 wv = {cvtpk(a[0], a[1]), cvtpk(a[2], a[3]),
                cvtpk(a[4], a[5]), cvtpk(a[6], a[7])};
    attb[kt] = __builtin_bit_cast(short8, wv);
  }

  // out-proj col tile w
  short8 wof[8];
#pragma unroll
  for (int kt = 0; kt < 8; ++kt)
    wof[kt] = *(const short8*)(Wo2 + (w * 8 + kt) * 512 + lane * 8);

  f32x16 zc;
#pragma unroll
  for (int j = 0; j < 16; ++j) zc[j] = 0.f;
  f32x16 acc = MFMA32(attb[0], wof[0], zc);
#pragma unroll
  for (int kt = 1; kt < 8; ++kt) acc = MFMA32(attb[kt], wof[kt], acc);

  float bov = bo[w * 32 + rr];
  float* op = out + (size_t)(b * 4096 + qt32 * 32) * 128 + w * 32 + rr;
#pragma unroll
  for (int r = 0; r < 16; ++r) {
    int q = (r & 3) + 8 * (r >> 2) + 4 * hi;
    op[q * 128] = acc[r] + bov;
  }
}

// ---------------------------------------------------------------------------
extern "C" void kernel_launch(void* const* d_in, const int* in_sizes, int n_in,
                              void* d_out, int out_size, void* d_ws, size_t ws_size,
                              hipStream_t stream) {
  const float* x  = (const float*)d_in[0];
  const float* Wq = (const float*)d_in[1];
  const float* bq = (const float*)d_in[2];
  const float* Wk = (const float*)d_in[3];
  const float* bk = (const float*)d_in[4];
  const float* Wv = (const float*)d_in[5];
  const float* bv = (const float*)d_in[6];
  const float* Wo = (const float*)d_in[7];
  const float* bo = (const float*)d_in[8];

  const size_t NE = 4u * 4096u * 128u;       // 2M elems per tensor
  unsigned short* Q2  = (unsigned short*)d_ws;
  unsigned short* K2  = Q2 + NE;
  unsigned short* V2  = K2 + NE;
  unsigned short* Wo2 = V2 + NE;             // 16384 elems
  unsigned short* PA  = Wo2 + 16384;         // 16 * 128 * 4096 = 8M elems
  float2*         ML2 = (float2*)(PA + (size_t)16 * 128 * 4096);  // 64K float2

  k_proj<<<256, 256, 0, stream>>>(x, Wq, bq, Wk, bk, Wv, bv, Wo, Q2, K2, V2, Wo2);
  k_attn<<<512, 256, 0, stream>>>(Q2, K2, V2, PA, ML2);
  k_merge<<<512, 256, 0, stream>>>(PA, ML2, Wo2, bo, (float*)d_out);
}

// Round 15
// 81.509 us; speedup vs baseline: 1.5974x; 1.0868x over previous
//
#include <hip/hip_runtime.h>
#include <stdint.h>

typedef __attribute__((ext_vector_type(8))) short short8;
typedef __attribute__((ext_vector_type(4))) float f32x4;
typedef __attribute__((ext_vector_type(16))) float f32x16;
typedef __attribute__((ext_vector_type(4))) int i32x4;
typedef __attribute__((ext_vector_type(2))) int i32x2;

#define MFMA16(a, b, c) __builtin_amdgcn_mfma_f32_16x16x32_bf16((a), (b), (c), 0, 0, 0)
#define MFMA32(a, b, c) __builtin_amdgcn_mfma_f32_32x32x16_bf16((a), (b), (c), 0, 0, 0)

typedef __attribute__((address_space(1))) const void GVoid;
typedef __attribute__((address_space(3))) void LVoid;
#define GLDS16(g, l) __builtin_amdgcn_global_load_lds((GVoid*)(g), (LVoid*)(l), 16, 0, 0)

#define L2E 1.4426950408889634f

__device__ __forceinline__ unsigned short f2bf(float f) {
  unsigned int u = __builtin_bit_cast(unsigned int, f);
  u += 0x7fffu + ((u >> 16) & 1u);   // RNE (finite values only)
  return (unsigned short)(u >> 16);
}
__device__ __forceinline__ float bf2f(unsigned short u) {
  return __builtin_bit_cast(float, (unsigned int)u << 16);
}

// permlane32_swap via builtin: two simultaneously-live results -> distinct regs
// guaranteed (inline-asm "+v","+v" self-swap was R3's bug).
__device__ __forceinline__ i32x2 pls(int a, int b) {
  return __builtin_amdgcn_permlane32_swap(a, b, false, false);
}
__device__ __forceinline__ float fasf(int x) { return __builtin_bit_cast(float, x); }
__device__ __forceinline__ int iasi(float x) { return __builtin_bit_cast(int, x); }

__device__ __forceinline__ int cvtpk(float lo, float hi) {
  int d;
  asm("v_cvt_pk_bf16_f32 %0, %1, %2" : "=v"(d) : "v"(lo), "v"(hi));
  return d;
}

// ---------------------------------------------------------------------------
// Kernel 1: Q/K/V projections, fragment-tiled outputs. Grid 768 = 3 W x 256
// row-blocks — each block does ONE (W, 64-row) pair (R14 ran all 3 W serially
// per block with 2 syncs each; this removes the serial chain, 3 blocks/CU).
//   Q2/K2: elem[(b*128 + tile)*4096 + kt*512 + ((h>>3)&1)*256 + (s&31)*8 + (h&7)]
//   V2:    elem[(b*128 + tile)*4096 + ((s>>4)&1)*2048 + (d>>5)*512
//               + ((s>>3)&1)*256 + (d&31)*8 + (s&7)]
//   Wo2:   elem[((oc>>5)*8 + (h>>4))*512 + ((h>>3)&1)*256 + (oc&31)*8 + (h&7)]
// Q pre-scaled by 1/sqrt(128). Q2/K2 stores via LDS-transpose staging ->
// coalesced 16B chunks.
// ---------------------------------------------------------------------------
__global__ __launch_bounds__(256) void k_proj(
    const float* __restrict__ x,
    const float* __restrict__ Wq, const float* __restrict__ bq,
    const float* __restrict__ Wk, const float* __restrict__ bk,
    const float* __restrict__ Wv, const float* __restrict__ bv,
    const float* __restrict__ Wo,
    unsigned short* __restrict__ Q2, unsigned short* __restrict__ K2,
    unsigned short* __restrict__ V2, unsigned short* __restrict__ Wo2)
{
  __shared__ __align__(16) unsigned short wt[128 * 128];  // swizzled W^T, 32KB
  __shared__ __align__(16) unsigned short st[64 * 136];   // store-stage, 17KB
  const int tid  = threadIdx.x;
  const int lane = tid & 63;
  const int wid  = tid >> 6;
  const int l15  = lane & 15;
  const int g    = lane >> 4;
  const int wI   = blockIdx.x >> 8;      // 0=Q, 1=K, 2=V
  const int blk  = blockIdx.x & 255;
  const int r0   = blk * 64 + wid * 16;

  if (blockIdx.x == 0) {
    for (int e = tid; e < 16384; e += 256) {
      int j = e & 7, ln = (e >> 3) & 63, kt = (e >> 9) & 7, dt = e >> 12;
      int h = kt * 16 + (ln >> 5) * 8 + j, oc = dt * 32 + (ln & 31);
      Wo2[e] = f2bf(Wo[h * 128 + oc]);
    }
  }

  short8 af[4];
  {
    const float* xp = x + (r0 + l15) * 128 + g * 8;
#pragma unroll
    for (int kt = 0; kt < 4; ++kt) {
      float4 v0 = *(const float4*)(xp + kt * 32);
      float4 v1 = *(const float4*)(xp + kt * 32 + 4);
      short8 a;
      a[0] = (short)f2bf(v0.x); a[1] = (short)f2bf(v0.y);
      a[2] = (short)f2bf(v0.z); a[3] = (short)f2bf(v0.w);
      a[4] = (short)f2bf(v1.x); a[5] = (short)f2bf(v1.y);
      a[6] = (short)f2bf(v1.z); a[7] = (short)f2bf(v1.w);
      af[kt] = a;
    }
  }

  const float* W  = (wI == 0) ? Wq : (wI == 1) ? Wk : Wv;
  const float* bv_ = (wI == 0) ? bq : (wI == 1) ? bk : bv;

  for (int i = 0; i < 64; ++i) {
    int idx = i * 256 + tid;
    int k = idx >> 7, n = idx & 127;
    int cs = (k >> 3) ^ (n & 7);
    wt[n * 128 + cs * 8 + (k & 7)] = f2bf(W[idx]);
  }
  __syncthreads();

  float bias[8];
#pragma unroll
  for (int nt = 0; nt < 8; ++nt) bias[nt] = bv_[nt * 16 + l15];

  f32x4 acc[8];
#pragma unroll
  for (int nt = 0; nt < 8; ++nt) acc[nt] = (f32x4){0.f, 0.f, 0.f, 0.f};

#pragma unroll
  for (int nt = 0; nt < 8; ++nt) {
    const int n = nt * 16 + l15;
#pragma unroll
    for (int ks = 0; ks < 4; ++ks) {
      int cs = (ks * 4 + g) ^ (n & 7);
      short8 bf = *(const short8*)&wt[n * 128 + cs * 8];
      acc[nt] = MFMA16(af[ks], bf, acc[nt]);
    }
  }

  // D layout: col = nt*16 + l15 (h/d dim), row m = r0 + g*4 + r (s dim)
  if (wI < 2) {
    const float sc = (wI == 0) ? 0.08838834764831845f : 1.0f;  // 1/sqrt(128)
    // stage to padded LDS tile [64 rows][136 cols]
#pragma unroll
    for (int nt = 0; nt < 8; ++nt) {
      int col = nt * 16 + l15;
#pragma unroll
      for (int r = 0; r < 4; ++r)
        st[(wid * 16 + g * 4 + r) * 136 + col] = f2bf((acc[nt][r] + bias[nt]) * sc);
    }
    __syncthreads();
    // coalesced fragment-order writes: 1024 chunks of 16B, 4 per thread
    unsigned short* Og = (wI == 0) ? Q2 : K2;
#pragma unroll
    for (int c4 = 0; c4 < 4; ++c4) {
      int c = c4 * 256 + tid;
      int T = c >> 9, cc = c & 511;
      int kt = cc >> 6, hib = (cc >> 5) & 1, s32 = cc & 31;
      int m0 = blk * 64 + T * 32;
      int bb = m0 >> 12, tile = (m0 & 4095) >> 5;
      short8 v = *(const short8*)&st[(T * 32 + s32) * 136 + kt * 16 + hib * 8];
      *(short8*)&Og[(size_t)(bb * 128 + tile) * 4096 + cc * 8] = v;
    }
  } else {
#pragma unroll
    for (int nt = 0; nt < 8; ++nt) {
      int col = nt * 16 + l15;
      int m0 = r0 + g * 4;
      int bb = m0 >> 12, srow = m0 & 4095;
      int idx = (bb * 128 + (srow >> 5)) * 4096 + ((srow >> 4) & 1) * 2048 +
                (col >> 5) * 512 + ((srow >> 3) & 1) * 256 + (col & 31) * 8 +
                (srow & 7);
      ushort4 pk;
      pk.x = f2bf(acc[nt][0] + bias[nt]);
      pk.y = f2bf(acc[nt][1] + bias[nt]);
      pk.z = f2bf(acc[nt][2] + bias[nt]);
      pk.w = f2bf(acc[nt][3] + bias[nt]);
      *(ushort4*)&V2[idx] = pk;
    }
  }
}

// ---------------------------------------------------------------------------
// Kernel 2: flash attention partials (unchanged from R14).
// Grid 512 = (4 b) x (32 q-supertiles of 128 rows) x (4 KV quarters);
// 256 thr = 4 waves x 32 q-rows; TWO independent blocks per CU.
// KVBLK=64, 16 iters; double-buffered 32KB K+V tile, counted vmcnt(8);
// two raw s_barriers per iter.
// ---------------------------------------------------------------------------
__global__ __launch_bounds__(256, 2) void k_attn(
    const unsigned short* __restrict__ Q2,
    const unsigned short* __restrict__ K2,
    const unsigned short* __restrict__ V2,
    unsigned short* __restrict__ PA,
    float2* __restrict__ ML2)
{
  __shared__ __align__(16) char smem[66560];   // 2 x 32KB bufs + 1KB RBUF
  const int tid = threadIdx.x, lane = tid & 63, wid = tid >> 6;   // wid 0..3
  const int rr = lane & 31, hi = lane >> 5;
  // XCD-aware: batch b pinned to XCD pair {2b,2b+1}
  const int p = blockIdx.x;
  const int b = (p & 7) >> 1;
  const int idx = ((p >> 3) << 1) | (p & 1);   // 0..127
  const int qst = idx >> 2, kvq = idx & 3;     // qst 0..31
  const int q0tile = qst * 4 + wid;            // 32q-tile index 0..127

  // Q fragments (pre-scaled): 8 coalesced 1KB loads
  short8 qf[8];
  {
    const unsigned short* qp = Q2 + (size_t)(b * 128 + q0tile) * 4096 + lane * 8;
#pragma unroll
    for (int kt = 0; kt < 8; ++kt) qf[kt] = *(const short8*)(qp + kt * 512);
  }

  // staging sources: thread tid stages 8 x 16B chunks (2 per 8KB tile)
  const unsigned short* gsrc[4];
  gsrc[0] = K2 + (size_t)(b * 128 + kvq * 32 + 0) * 4096 + tid * 8;
  gsrc[1] = K2 + (size_t)(b * 128 + kvq * 32 + 1) * 4096 + tid * 8;
  gsrc[2] = V2 + (size_t)(b * 128 + kvq * 32 + 0) * 4096 + tid * 8;
  gsrc[3] = V2 + (size_t)(b * 128 + kvq * 32 + 1) * 4096 + tid * 8;

  char* const rbuf = smem + 65536 + wid * 128;

  // prologue: stage tile 0 into buf 0
#pragma unroll
  for (int i = 0; i < 4; ++i) {
    GLDS16(gsrc[i], smem + i * 8192 + tid * 16);
    GLDS16(gsrc[i] + 2048, smem + i * 8192 + 4096 + tid * 16);
  }

  f32x16 O[4];
#pragma unroll
  for (int dt = 0; dt < 4; ++dt)
#pragma unroll
    for (int j = 0; j < 16; ++j) O[dt][j] = 0.f;
  f32x16 zc;
#pragma unroll
  for (int j = 0; j < 16; ++j) zc[j] = 0.f;
  float mS = -3.0e38f, lS = 0.f;

  for (int t = 0; t < 16; ++t) {
    char* const b0 = smem + (t & 1) * 32768;
    if (t < 15) {
      char* const bn = smem + ((t + 1) & 1) * 32768;
      const size_t adv = (size_t)(t + 1) * 8192;
#pragma unroll
      for (int i = 0; i < 4; ++i) {
        GLDS16(gsrc[i] + adv, bn + i * 8192 + tid * 16);
        GLDS16(gsrc[i] + adv + 2048, bn + i * 8192 + 4096 + tid * 16);
      }
      asm volatile("s_waitcnt vmcnt(8)" ::: "memory");  // my tile-t slices landed
    } else {
      asm volatile("s_waitcnt vmcnt(0)" ::: "memory");
    }
    __builtin_amdgcn_s_barrier();                       // ALL tile-t slices in LDS
    __builtin_amdgcn_sched_barrier(0);

    // ---- QK^T swapped: two 32-kv subtiles, D[kv=regs][q=lane&31] ----
    f32x16 sT0, sT1;
    __builtin_amdgcn_s_setprio(1);
    {
      short8 kf[8];
#pragma unroll
      for (int kt = 0; kt < 8; ++kt)
        kf[kt] = *(const short8*)(b0 + kt * 1024 + lane * 16);
      sT0 = MFMA32(kf[0], qf[0], zc);
#pragma unroll
      for (int kt = 1; kt < 8; ++kt) sT0 = MFMA32(kf[kt], qf[kt], sT0);
    }
    {
      short8 kf[8];
#pragma unroll
      for (int kt = 0; kt < 8; ++kt)
        kf[kt] = *(const short8*)(b0 + 8192 + kt * 1024 + lane * 16);
      sT1 = MFMA32(kf[0], qf[0], zc);
#pragma unroll
      for (int kt = 1; kt < 8; ++kt) sT1 = MFMA32(kf[kt], qf[kt], sT1);
    }
    __builtin_amdgcn_s_setprio(0);

    // ---- online softmax over 64 kv; kv row of reg r = (r&3)+8*(r>>2)+4*hi --
    float pm = -3.0e38f;
#pragma unroll
    for (int r = 0; r < 16; ++r) pm = fmaxf(pm, fmaxf(sT0[r], sT1[r]));
    { i32x2 r = pls(iasi(pm), iasi(pm)); pm = fmaxf(fasf(r[0]), fasf(r[1])); }

    if (!__all(pm - mS <= 8.0f)) {          // defer-max (THR=8)
      float mnew = fmaxf(mS, pm);
      float fsc = exp2f((mS - mnew) * L2E);
      mS = mnew;
      lS *= fsc;
      if (hi == 0) *(float*)(rbuf + rr * 4) = fsc;
      f32x4 fr[4];
#pragma unroll
      for (int i = 0; i < 4; ++i)
        fr[i] = *(const f32x4*)(rbuf + i * 32 + hi * 16);
#pragma unroll
      for (int dt = 0; dt < 4; ++dt)
#pragma unroll
        for (int i = 0; i < 4; ++i)
#pragma unroll
          for (int j = 0; j < 4; ++j) O[dt][i * 4 + j] *= fr[i][j];
    }

    const float mL = mS * L2E;
    float pv0[16], pv1[16];
    float ts = 0.f;
#pragma unroll
    for (int r = 0; r < 16; ++r) {
      pv0[r] = exp2f(sT0[r] * L2E - mL);
      pv1[r] = exp2f(sT1[r] * L2E - mL);
      ts += pv0[r] + pv1[r];
    }
    { i32x2 r = pls(iasi(ts), iasi(ts)); ts = fasf(r[0]) + fasf(r[1]); }
    lS += ts;

    // ---- P -> PV A-fragments fully in registers (T12), 4 frags ----
    short8 pa[4];
    {
      int dw[8];
#pragma unroll
      for (int m = 0; m < 8; ++m) dw[m] = cvtpk(pv0[2 * m], pv0[2 * m + 1]);
      i32x2 ra = pls(dw[0], dw[2]);
      i32x2 rb = pls(dw[1], dw[3]);
      i32x2 rc = pls(dw[4], dw[6]);
      i32x2 rd = pls(dw[5], dw[7]);
      i32x4 w0 = {ra[0], rb[0], ra[1], rb[1]};
      i32x4 w1 = {rc[0], rd[0], rc[1], rd[1]};
      pa[0] = __builtin_bit_cast(short8, w0);
      pa[1] = __builtin_bit_cast(short8, w1);
    }
    {
      int dw[8];
#pragma unroll
      for (int m = 0; m < 8; ++m) dw[m] = cvtpk(pv1[2 * m], pv1[2 * m + 1]);
      i32x2 ra = pls(dw[0], dw[2]);
      i32x2 rb = pls(dw[1], dw[3]);
      i32x2 rc = pls(dw[4], dw[6]);
      i32x2 rd = pls(dw[5], dw[7]);
      i32x4 w0 = {ra[0], rb[0], ra[1], rb[1]};
      i32x4 w1 = {rc[0], rd[0], rc[1], rd[1]};
      pa[2] = __builtin_bit_cast(short8, w0);
      pa[3] = __builtin_bit_cast(short8, w1);
    }

    // ---- PV: O[q][d] += P[q][kv64] * V[kv64][d] ----
    __builtin_amdgcn_s_setprio(1);
#pragma unroll
    for (int ks = 0; ks < 4; ++ks) {
      const char* vb = b0 + 16384 + (ks >> 1) * 8192 + (ks & 1) * 4096;
      short8 vf[4];
#pragma unroll
      for (int dt = 0; dt < 4; ++dt)
        vf[dt] = *(const short8*)(vb + dt * 1024 + lane * 16);
#pragma unroll
      for (int dt = 0; dt < 4; ++dt) O[dt] = MFMA32(pa[ks], vf[dt], O[dt]);
    }
    __builtin_amdgcn_s_setprio(0);

    // trailing barrier: all waves done reading b0 -> free for restage at t+1
    __builtin_amdgcn_s_barrier();
  }

  // ---- epilogue: write partial A-frag image + (m,l); no LDS needed ----
  unsigned short* pab = PA + ((size_t)(b * 4 + kvq) * 128 + q0tile) * 4096;
#pragma unroll
  for (int dt = 0; dt < 4; ++dt) {
    int kt = dt * 2 + (rr >> 4);
#pragma unroll
    for (int r = 0; r < 16; ++r) {
      int q = (r & 3) + 8 * (r >> 2) + 4 * hi;
      int e = kt * 512 + (((rr >> 3) & 1) * 32 + q) * 8 + (rr & 7);
      pab[e] = f2bf(O[dt][r]);
    }
  }
  if (hi == 0)
    ML2[(size_t)(b * 4 + kvq) * 4096 + q0tile * 32 + rr] = make_float2(mS, lS);
}

// ---------------------------------------------------------------------------
// Kernel 3: merge 4 KV-quarter partials + fused output projection.
// Grid 512, 256 thr = 4 waves; wave w -> out cols [w*32, w*32+32).
// XCD-aware block mapping (NEW): merge block for batch b uses the same
// p->(b,qt32) swizzle as k_attn, so PA reads hit the L2 of the XCD pair
// {2b,2b+1} that produced them (linear mapping caused cross-XCD misses).
// ---------------------------------------------------------------------------
__global__ __launch_bounds__(256) void k_merge(
    const unsigned short* __restrict__ PA,
    const float2* __restrict__ ML2,
    const unsigned short* __restrict__ Wo2,
    const float* __restrict__ bo,
    float* __restrict__ out)
{
  const int tid = threadIdx.x, lane = tid & 63, w = tid >> 6;
  const int rr = lane & 31, hi = lane >> 5;
  const int p = blockIdx.x;
  const int b = (p & 7) >> 1;
  const int qt32 = ((p >> 3) << 1) | (p & 1);   // 0..127

  // per-lane (q = rr) merge coefficients
  float mh[4], lh[4];
#pragma unroll
  for (int h = 0; h < 4; ++h) {
    float2 ml = ML2[(size_t)(b * 4 + h) * 4096 + qt32 * 32 + rr];
    mh[h] = ml.x; lh[h] = ml.y;
  }
  float M = fmaxf(fmaxf(mh[0], mh[1]), fmaxf(mh[2], mh[3]));
  float ch[4], L = 0.f;
#pragma unroll
  for (int h = 0; h < 4; ++h) { ch[h] = exp2f((mh[h] - M) * L2E); L += ch[h] * lh[h]; }
  float iL = 1.0f / L;
#pragma unroll
  for (int h = 0; h < 4; ++h) ch[h] *= iL;

  // merged att A-fragments (lane row = q = lane&31 -> ch is per-lane correct)
  short8 attb[8];
#pragma unroll
  for (int kt = 0; kt < 8; ++kt) {
    float a[8];
#pragma unroll
    for (int j = 0; j < 8; ++j) a[j] = 0.f;
#pragma unroll
    for (int h = 0; h < 4; ++h) {
      short8 ph = *(const short8*)(PA + ((size_t)(b * 4 + h) * 128 + qt32) * 4096 +
                                   kt * 512 + lane * 8);
#pragma unroll
      for (int j = 0; j < 8; ++j)
        a[j] += ch[h] * bf2f((unsigned short)ph[j]);
    }
    i32x4 wv = {cvtpk(a[0], a[1]), cvtpk(a[2], a[3]),
                cvtpk(a[4], a[5]), cvtpk(a[6], a[7])};
    attb[kt] = __builtin_bit_cast(short8, wv);
  }

  // out-proj col tile w
  short8 wof[8];
#pragma unroll
  for (int kt = 0; kt < 8; ++kt)
    wof[kt] = *(const short8*)(Wo2 + (w * 8 + kt) * 512 + lane * 8);

  f32x16 zc;
#pragma unroll
  for (int j = 0; j < 16; ++j) zc[j] = 0.f;
  f32x16 acc = MFMA32(attb[0], wof[0], zc);
#pragma unroll
  for (int kt = 1; kt < 8; ++kt) acc = MFMA32(attb[kt], wof[kt], acc);

  float bov = bo[w * 32 + rr];
  float* op = out + (size_t)(b * 4096 + qt32 * 32) * 128 + w * 32 + rr;
#pragma unroll
  for (int r = 0; r < 16; ++r) {
    int q = (r & 3) + 8 * (r >> 2) + 4 * hi;
    op[q * 128] = acc[r] + bov;
  }
}

// ---------------------------------------------------------------------------
extern "C" void kernel_launch(void* const* d_in, const int* in_sizes, int n_in,
                              void* d_out, int out_size, void* d_ws, size_t ws_size,
                              hipStream_t stream) {
  const float* x  = (const float*)d_in[0];
  const float* Wq = (const float*)d_in[1];
  const float* bq = (const float*)d_in[2];
  const float* Wk = (const float*)d_in[3];
  const float* bk = (const float*)d_in[4];
  const float* Wv = (const float*)d_in[5];
  const float* bv = (const float*)d_in[6];
  const float* Wo = (const float*)d_in[7];
  const float* bo = (const float*)d_in[8];

  const size_t NE = 4u * 4096u * 128u;       // 2M elems per tensor
  unsigned short* Q2  = (unsigned short*)d_ws;
  unsigned short* K2  = Q2 + NE;
  unsigned short* V2  = K2 + NE;
  unsigned short* Wo2 = V2 + NE;             // 16384 elems
  unsigned short* PA  = Wo2 + 16384;         // 16 * 128 * 4096 = 8M elems
  float2*         ML2 = (float2*)(PA + (size_t)16 * 128 * 4096);  // 64K float2

  k_proj<<<768, 256, 0, stream>>>(x, Wq, bq, Wk, bk, Wv, bv, Wo, Q2, K2, V2, Wo2);
  k_attn<<<512, 256, 0, stream>>>(Q2, K2, V2, PA, ML2);
  k_merge<<<512, 256, 0, stream>>>(PA, ML2, Wo2, bo, (float*)d_out);
}

// Round 16
// 77.276 us; speedup vs baseline: 1.6850x; 1.0548x over previous
//
#include <hip/hip_runtime.h>
#include <stdint.h>

typedef __attribute__((ext_vector_type(8))) short short8;
typedef __attribute__((ext_vector_type(4))) float f32x4;
typedef __attribute__((ext_vector_type(16))) float f32x16;
typedef __attribute__((ext_vector_type(4))) int i32x4;
typedef __attribute__((ext_vector_type(2))) int i32x2;

#define MFMA16(a, b, c) __builtin_amdgcn_mfma_f32_16x16x32_bf16((a), (b), (c), 0, 0, 0)
#define MFMA32(a, b, c) __builtin_amdgcn_mfma_f32_32x32x16_bf16((a), (b), (c), 0, 0, 0)

typedef __attribute__((address_space(1))) const void GVoid;
typedef __attribute__((address_space(3))) void LVoid;
#define GLDS16(g, l) __builtin_amdgcn_global_load_lds((GVoid*)(g), (LVoid*)(l), 16, 0, 0)

#define L2E 1.4426950408889634f

__device__ __forceinline__ unsigned short f2bf(float f) {
  unsigned int u = __builtin_bit_cast(unsigned int, f);
  u += 0x7fffu + ((u >> 16) & 1u);   // RNE (finite values only)
  return (unsigned short)(u >> 16);
}
__device__ __forceinline__ float bf2f(unsigned short u) {
  return __builtin_bit_cast(float, (unsigned int)u << 16);
}

// raw v_exp_f32: args here are always <= 0; denormal flush-to-zero is the
// WANTED semantics (exp of very negative = 0). Avoids the OCML exp2f libcall
// (~6-10 VALU instrs of range handling) that the no-fast-math build emits.
__device__ __forceinline__ float fexp2(float x) {
  return __builtin_amdgcn_exp2f(x);
}

// permlane32_swap via builtin: two simultaneously-live results -> distinct regs
// guaranteed (inline-asm "+v","+v" self-swap was R3's bug).
__device__ __forceinline__ i32x2 pls(int a, int b) {
  return __builtin_amdgcn_permlane32_swap(a, b, false, false);
}
__device__ __forceinline__ float fasf(int x) { return __builtin_bit_cast(float, x); }
__device__ __forceinline__ int iasi(float x) { return __builtin_bit_cast(int, x); }

__device__ __forceinline__ int cvtpk(float lo, float hi) {
  int d;
  asm("v_cvt_pk_bf16_f32 %0, %1, %2" : "=v"(d) : "v"(lo), "v"(hi));
  return d;
}

// ---------------------------------------------------------------------------
// Kernel 1: Q/K/V projections, fragment-tiled outputs. Grid 768 = 3 W x 256
// row-blocks — each block does ONE (W, 64-row) pair.
//   Q2/K2: elem[(b*128 + tile)*4096 + kt*512 + ((h>>3)&1)*256 + (s&31)*8 + (h&7)]
//   V2:    elem[(b*128 + tile)*4096 + ((s>>4)&1)*2048 + (d>>5)*512
//               + ((s>>3)&1)*256 + (d&31)*8 + (s&7)]
//   Wo2:   elem[((oc>>5)*8 + (h>>4))*512 + ((h>>3)&1)*256 + (oc&31)*8 + (h&7)]
// Q pre-scaled by 1/sqrt(128). Q2/K2 stores via LDS-transpose staging ->
// coalesced 16B chunks.
// ---------------------------------------------------------------------------
__global__ __launch_bounds__(256) void k_proj(
    const float* __restrict__ x,
    const float* __restrict__ Wq, const float* __restrict__ bq,
    const float* __restrict__ Wk, const float* __restrict__ bk,
    const float* __restrict__ Wv, const float* __restrict__ bv,
    const float* __restrict__ Wo,
    unsigned short* __restrict__ Q2, unsigned short* __restrict__ K2,
    unsigned short* __restrict__ V2, unsigned short* __restrict__ Wo2)
{
  __shared__ __align__(16) unsigned short wt[128 * 128];  // swizzled W^T, 32KB
  __shared__ __align__(16) unsigned short st[64 * 136];   // store-stage, 17KB
  const int tid  = threadIdx.x;
  const int lane = tid & 63;
  const int wid  = tid >> 6;
  const int l15  = lane & 15;
  const int g    = lane >> 4;
  const int wI   = blockIdx.x >> 8;      // 0=Q, 1=K, 2=V
  const int blk  = blockIdx.x & 255;
  const int r0   = blk * 64 + wid * 16;

  if (blockIdx.x == 0) {
    for (int e = tid; e < 16384; e += 256) {
      int j = e & 7, ln = (e >> 3) & 63, kt = (e >> 9) & 7, dt = e >> 12;
      int h = kt * 16 + (ln >> 5) * 8 + j, oc = dt * 32 + (ln & 31);
      Wo2[e] = f2bf(Wo[h * 128 + oc]);
    }
  }

  short8 af[4];
  {
    const float* xp = x + (r0 + l15) * 128 + g * 8;
#pragma unroll
    for (int kt = 0; kt < 4; ++kt) {
      float4 v0 = *(const float4*)(xp + kt * 32);
      float4 v1 = *(const float4*)(xp + kt * 32 + 4);
      short8 a;
      a[0] = (short)f2bf(v0.x); a[1] = (short)f2bf(v0.y);
      a[2] = (short)f2bf(v0.z); a[3] = (short)f2bf(v0.w);
      a[4] = (short)f2bf(v1.x); a[5] = (short)f2bf(v1.y);
      a[6] = (short)f2bf(v1.z); a[7] = (short)f2bf(v1.w);
      af[kt] = a;
    }
  }

  const float* W  = (wI == 0) ? Wq : (wI == 1) ? Wk : Wv;
  const float* bv_ = (wI == 0) ? bq : (wI == 1) ? bk : bv;

  for (int i = 0; i < 64; ++i) {
    int idx = i * 256 + tid;
    int k = idx >> 7, n = idx & 127;
    int cs = (k >> 3) ^ (n & 7);
    wt[n * 128 + cs * 8 + (k & 7)] = f2bf(W[idx]);
  }
  __syncthreads();

  float bias[8];
#pragma unroll
  for (int nt = 0; nt < 8; ++nt) bias[nt] = bv_[nt * 16 + l15];

  f32x4 acc[8];
#pragma unroll
  for (int nt = 0; nt < 8; ++nt) acc[nt] = (f32x4){0.f, 0.f, 0.f, 0.f};

#pragma unroll
  for (int nt = 0; nt < 8; ++nt) {
    const int n = nt * 16 + l15;
#pragma unroll
    for (int ks = 0; ks < 4; ++ks) {
      int cs = (ks * 4 + g) ^ (n & 7);
      short8 bf = *(const short8*)&wt[n * 128 + cs * 8];
      acc[nt] = MFMA16(af[ks], bf, acc[nt]);
    }
  }

  // D layout: col = nt*16 + l15 (h/d dim), row m = r0 + g*4 + r (s dim)
  if (wI < 2) {
    const float sc = (wI == 0) ? 0.08838834764831845f : 1.0f;  // 1/sqrt(128)
    // stage to padded LDS tile [64 rows][136 cols]
#pragma unroll
    for (int nt = 0; nt < 8; ++nt) {
      int col = nt * 16 + l15;
#pragma unroll
      for (int r = 0; r < 4; ++r)
        st[(wid * 16 + g * 4 + r) * 136 + col] = f2bf((acc[nt][r] + bias[nt]) * sc);
    }
    __syncthreads();
    // coalesced fragment-order writes: 1024 chunks of 16B, 4 per thread
    unsigned short* Og = (wI == 0) ? Q2 : K2;
#pragma unroll
    for (int c4 = 0; c4 < 4; ++c4) {
      int c = c4 * 256 + tid;
      int T = c >> 9, cc = c & 511;
      int kt = cc >> 6, hib = (cc >> 5) & 1, s32 = cc & 31;
      int m0 = blk * 64 + T * 32;
      int bb = m0 >> 12, tile = (m0 & 4095) >> 5;
      short8 v = *(const short8*)&st[(T * 32 + s32) * 136 + kt * 16 + hib * 8];
      *(short8*)&Og[(size_t)(bb * 128 + tile) * 4096 + cc * 8] = v;
    }
  } else {
#pragma unroll
    for (int nt = 0; nt < 8; ++nt) {
      int col = nt * 16 + l15;
      int m0 = r0 + g * 4;
      int bb = m0 >> 12, srow = m0 & 4095;
      int idx = (bb * 128 + (srow >> 5)) * 4096 + ((srow >> 4) & 1) * 2048 +
                (col >> 5) * 512 + ((srow >> 3) & 1) * 256 + (col & 31) * 8 +
                (srow & 7);
      ushort4 pk;
      pk.x = f2bf(acc[nt][0] + bias[nt]);
      pk.y = f2bf(acc[nt][1] + bias[nt]);
      pk.z = f2bf(acc[nt][2] + bias[nt]);
      pk.w = f2bf(acc[nt][3] + bias[nt]);
      *(ushort4*)&V2[idx] = pk;
    }
  }
}

// ---------------------------------------------------------------------------
// Kernel 2: flash attention partials (structure unchanged from R14/R15;
// exp2f -> raw v_exp_f32 this round).
// Grid 512 = (4 b) x (32 q-supertiles of 128 rows) x (4 KV quarters);
// 256 thr = 4 waves x 32 q-rows; TWO independent blocks per CU.
// KVBLK=64, 16 iters; double-buffered 32KB K+V tile, counted vmcnt(8);
// two raw s_barriers per iter.
// ---------------------------------------------------------------------------
__global__ __launch_bounds__(256, 2) void k_attn(
    const unsigned short* __restrict__ Q2,
    const unsigned short* __restrict__ K2,
    const unsigned short* __restrict__ V2,
    unsigned short* __restrict__ PA,
    float2* __restrict__ ML2)
{
  __shared__ __align__(16) char smem[66560];   // 2 x 32KB bufs + 1KB RBUF
  const int tid = threadIdx.x, lane = tid & 63, wid = tid >> 6;   // wid 0..3
  const int rr = lane & 31, hi = lane >> 5;
  // XCD-aware: batch b pinned to XCD pair {2b,2b+1}
  const int p = blockIdx.x;
  const int b = (p & 7) >> 1;
  const int idx = ((p >> 3) << 1) | (p & 1);   // 0..127
  const int qst = idx >> 2, kvq = idx & 3;     // qst 0..31
  const int q0tile = qst * 4 + wid;            // 32q-tile index 0..127

  // Q fragments (pre-scaled): 8 coalesced 1KB loads
  short8 qf[8];
  {
    const unsigned short* qp = Q2 + (size_t)(b * 128 + q0tile) * 4096 + lane * 8;
#pragma unroll
    for (int kt = 0; kt < 8; ++kt) qf[kt] = *(const short8*)(qp + kt * 512);
  }

  // staging sources: thread tid stages 8 x 16B chunks (2 per 8KB tile)
  const unsigned short* gsrc[4];
  gsrc[0] = K2 + (size_t)(b * 128 + kvq * 32 + 0) * 4096 + tid * 8;
  gsrc[1] = K2 + (size_t)(b * 128 + kvq * 32 + 1) * 4096 + tid * 8;
  gsrc[2] = V2 + (size_t)(b * 128 + kvq * 32 + 0) * 4096 + tid * 8;
  gsrc[3] = V2 + (size_t)(b * 128 + kvq * 32 + 1) * 4096 + tid * 8;

  char* const rbuf = smem + 65536 + wid * 128;

  // prologue: stage tile 0 into buf 0
#pragma unroll
  for (int i = 0; i < 4; ++i) {
    GLDS16(gsrc[i], smem + i * 8192 + tid * 16);
    GLDS16(gsrc[i] + 2048, smem + i * 8192 + 4096 + tid * 16);
  }

  f32x16 O[4];
#pragma unroll
  for (int dt = 0; dt < 4; ++dt)
#pragma unroll
    for (int j = 0; j < 16; ++j) O[dt][j] = 0.f;
  f32x16 zc;
#pragma unroll
  for (int j = 0; j < 16; ++j) zc[j] = 0.f;
  float mS = -3.0e38f, lS = 0.f;

  for (int t = 0; t < 16; ++t) {
    char* const b0 = smem + (t & 1) * 32768;
    if (t < 15) {
      char* const bn = smem + ((t + 1) & 1) * 32768;
      const size_t adv = (size_t)(t + 1) * 8192;
#pragma unroll
      for (int i = 0; i < 4; ++i) {
        GLDS16(gsrc[i] + adv, bn + i * 8192 + tid * 16);
        GLDS16(gsrc[i] + adv + 2048, bn + i * 8192 + 4096 + tid * 16);
      }
      asm volatile("s_waitcnt vmcnt(8)" ::: "memory");  // my tile-t slices landed
    } else {
      asm volatile("s_waitcnt vmcnt(0)" ::: "memory");
    }
    __builtin_amdgcn_s_barrier();                       // ALL tile-t slices in LDS
    __builtin_amdgcn_sched_barrier(0);

    // ---- QK^T swapped: two 32-kv subtiles, D[kv=regs][q=lane&31] ----
    f32x16 sT0, sT1;
    __builtin_amdgcn_s_setprio(1);
    {
      short8 kf[8];
#pragma unroll
      for (int kt = 0; kt < 8; ++kt)
        kf[kt] = *(const short8*)(b0 + kt * 1024 + lane * 16);
      sT0 = MFMA32(kf[0], qf[0], zc);
#pragma unroll
      for (int kt = 1; kt < 8; ++kt) sT0 = MFMA32(kf[kt], qf[kt], sT0);
    }
    {
      short8 kf[8];
#pragma unroll
      for (int kt = 0; kt < 8; ++kt)
        kf[kt] = *(const short8*)(b0 + 8192 + kt * 1024 + lane * 16);
      sT1 = MFMA32(kf[0], qf[0], zc);
#pragma unroll
      for (int kt = 1; kt < 8; ++kt) sT1 = MFMA32(kf[kt], qf[kt], sT1);
    }
    __builtin_amdgcn_s_setprio(0);

    // ---- online softmax over 64 kv; kv row of reg r = (r&3)+8*(r>>2)+4*hi --
    float pm = -3.0e38f;
#pragma unroll
    for (int r = 0; r < 16; ++r) pm = fmaxf(pm, fmaxf(sT0[r], sT1[r]));
    { i32x2 r = pls(iasi(pm), iasi(pm)); pm = fmaxf(fasf(r[0]), fasf(r[1])); }

    if (!__all(pm - mS <= 8.0f)) {          // defer-max (THR=8)
      float mnew = fmaxf(mS, pm);
      float fsc = fexp2((mS - mnew) * L2E);
      mS = mnew;
      lS *= fsc;
      if (hi == 0) *(float*)(rbuf + rr * 4) = fsc;
      f32x4 fr[4];
#pragma unroll
      for (int i = 0; i < 4; ++i)
        fr[i] = *(const f32x4*)(rbuf + i * 32 + hi * 16);
#pragma unroll
      for (int dt = 0; dt < 4; ++dt)
#pragma unroll
        for (int i = 0; i < 4; ++i)
#pragma unroll
          for (int j = 0; j < 4; ++j) O[dt][i * 4 + j] *= fr[i][j];
    }

    const float mL = mS * L2E;
    float pv0[16], pv1[16];
    float ts = 0.f;
#pragma unroll
    for (int r = 0; r < 16; ++r) {
      pv0[r] = fexp2(sT0[r] * L2E - mL);
      pv1[r] = fexp2(sT1[r] * L2E - mL);
      ts += pv0[r] + pv1[r];
    }
    { i32x2 r = pls(iasi(ts), iasi(ts)); ts = fasf(r[0]) + fasf(r[1]); }
    lS += ts;

    // ---- P -> PV A-fragments fully in registers (T12), 4 frags ----
    short8 pa[4];
    {
      int dw[8];
#pragma unroll
      for (int m = 0; m < 8; ++m) dw[m] = cvtpk(pv0[2 * m], pv0[2 * m + 1]);
      i32x2 ra = pls(dw[0], dw[2]);
      i32x2 rb = pls(dw[1], dw[3]);
      i32x2 rc = pls(dw[4], dw[6]);
      i32x2 rd = pls(dw[5], dw[7]);
      i32x4 w0 = {ra[0], rb[0], ra[1], rb[1]};
      i32x4 w1 = {rc[0], rd[0], rc[1], rd[1]};
      pa[0] = __builtin_bit_cast(short8, w0);
      pa[1] = __builtin_bit_cast(short8, w1);
    }
    {
      int dw[8];
#pragma unroll
      for (int m = 0; m < 8; ++m) dw[m] = cvtpk(pv1[2 * m], pv1[2 * m + 1]);
      i32x2 ra = pls(dw[0], dw[2]);
      i32x2 rb = pls(dw[1], dw[3]);
      i32x2 rc = pls(dw[4], dw[6]);
      i32x2 rd = pls(dw[5], dw[7]);
      i32x4 w0 = {ra[0], rb[0], ra[1], rb[1]};
      i32x4 w1 = {rc[0], rd[0], rc[1], rd[1]};
      pa[2] = __builtin_bit_cast(short8, w0);
      pa[3] = __builtin_bit_cast(short8, w1);
    }

    // ---- PV: O[q][d] += P[q][kv64] * V[kv64][d] ----
    __builtin_amdgcn_s_setprio(1);
#pragma unroll
    for (int ks = 0; ks < 4; ++ks) {
      const char* vb = b0 + 16384 + (ks >> 1) * 8192 + (ks & 1) * 4096;
      short8 vf[4];
#pragma unroll
      for (int dt = 0; dt < 4; ++dt)
        vf[dt] = *(const short8*)(vb + dt * 1024 + lane * 16);
#pragma unroll
      for (int dt = 0; dt < 4; ++dt) O[dt] = MFMA32(pa[ks], vf[dt], O[dt]);
    }
    __builtin_amdgcn_s_setprio(0);

    // trailing barrier: all waves done reading b0 -> free for restage at t+1
    __builtin_amdgcn_s_barrier();
  }

  // ---- epilogue: write partial A-frag image + (m,l); no LDS needed ----
  unsigned short* pab = PA + ((size_t)(b * 4 + kvq) * 128 + q0tile) * 4096;
#pragma unroll
  for (int dt = 0; dt < 4; ++dt) {
    int kt = dt * 2 + (rr >> 4);
#pragma unroll
    for (int r = 0; r < 16; ++r) {
      int q = (r & 3) + 8 * (r >> 2) + 4 * hi;
      int e = kt * 512 + (((rr >> 3) & 1) * 32 + q) * 8 + (rr & 7);
      pab[e] = f2bf(O[dt][r]);
    }
  }
  if (hi == 0)
    ML2[(size_t)(b * 4 + kvq) * 4096 + q0tile * 32 + rr] = make_float2(mS, lS);
}

// ---------------------------------------------------------------------------
// Kernel 3: merge 4 KV-quarter partials + fused output projection.
// Grid 512, 256 thr = 4 waves; wave w -> out cols [w*32, w*32+32).
// XCD-aware block mapping matches k_attn's producer mapping.
// ---------------------------------------------------------------------------
__global__ __launch_bounds__(256) void k_merge(
    const unsigned short* __restrict__ PA,
    const float2* __restrict__ ML2,
    const unsigned short* __restrict__ Wo2,
    const float* __restrict__ bo,
    float* __restrict__ out)
{
  const int tid = threadIdx.x, lane = tid & 63, w = tid >> 6;
  const int rr = lane & 31, hi = lane >> 5;
  const int p = blockIdx.x;
  const int b = (p & 7) >> 1;
  const int qt32 = ((p >> 3) << 1) | (p & 1);   // 0..127

  // per-lane (q = rr) merge coefficients
  float mh[4], lh[4];
#pragma unroll
  for (int h = 0; h < 4; ++h) {
    float2 ml = ML2[(size_t)(b * 4 + h) * 4096 + qt32 * 32 + rr];
    mh[h] = ml.x; lh[h] = ml.y;
  }
  float M = fmaxf(fmaxf(mh[0], mh[1]), fmaxf(mh[2], mh[3]));
  float ch[4], L = 0.f;
#pragma unroll
  for (int h = 0; h < 4; ++h) { ch[h] = fexp2((mh[h] - M) * L2E); L += ch[h] * lh[h]; }
  float iL = 1.0f / L;
#pragma unroll
  for (int h = 0; h < 4; ++h) ch[h] *= iL;

  // merged att A-fragments (lane row = q = lane&31 -> ch is per-lane correct)
  short8 attb[8];
#pragma unroll
  for (int kt = 0; kt < 8; ++kt) {
    float a[8];
#pragma unroll
    for (int j = 0; j < 8; ++j) a[j] = 0.f;
#pragma unroll
    for (int h = 0; h < 4; ++h) {
      short8 ph = *(const short8*)(PA + ((size_t)(b * 4 + h) * 128 + qt32) * 4096 +
                                   kt * 512 + lane * 8);
#pragma unroll
      for (int j = 0; j < 8; ++j)
        a[j] += ch[h] * bf2f((unsigned short)ph[j]);
    }
    i32x4 wv = {cvtpk(a[0], a[1]), cvtpk(a[2], a[3]),
                cvtpk(a[4], a[5]), cvtpk(a[6], a[7])};
    attb[kt] = __builtin_bit_cast(short8, wv);
  }

  // out-proj col tile w
  short8 wof[8];
#pragma unroll
  for (int kt = 0; kt < 8; ++kt)
    wof[kt] = *(const short8*)(Wo2 + (w * 8 + kt) * 512 + lane * 8);

  f32x16 zc;
#pragma unroll
  for (int j = 0; j < 16; ++j) zc[j] = 0.f;
  f32x16 acc = MFMA32(attb[0], wof[0], zc);
#pragma unroll
  for (int kt = 1; kt < 8; ++kt) acc = MFMA32(attb[kt], wof[kt], acc);

  float bov = bo[w * 32 + rr];
  float* op = out + (size_t)(b * 4096 + qt32 * 32) * 128 + w * 32 + rr;
#pragma unroll
  for (int r = 0; r < 16; ++r) {
    int q = (r & 3) + 8 * (r >> 2) + 4 * hi;
    op[q * 128] = acc[r] + bov;
  }
}

// ---------------------------------------------------------------------------
extern "C" void kernel_launch(void* const* d_in, const int* in_sizes, int n_in,
                              void* d_out, int out_size, void* d_ws, size_t ws_size,
                              hipStream_t stream) {
  const float* x  = (const float*)d_in[0];
  const float* Wq = (const float*)d_in[1];
  const float* bq = (const float*)d_in[2];
  const float* Wk = (const float*)d_in[3];
  const float* bk = (const float*)d_in[4];
  const float* Wv = (const float*)d_in[5];
  const float* bv = (const float*)d_in[6];
  const float* Wo = (const float*)d_in[7];
  const float* bo = (const float*)d_in[8];

  const size_t NE = 4u * 4096u * 128u;       // 2M elems per tensor
  unsigned short* Q2  = (unsigned short*)d_ws;
  unsigned short* K2  = Q2 + NE;
  unsigned short* V2  = K2 + NE;
  unsigned short* Wo2 = V2 + NE;             // 16384 elems
  unsigned short* PA  = Wo2 + 16384;         // 16 * 128 * 4096 = 8M elems
  float2*         ML2 = (float2*)(PA + (size_t)16 * 128 * 4096);  // 64K float2

  k_proj<<<768, 256, 0, stream>>>(x, Wq, bq, Wk, bk, Wv, bv, Wo, Q2, K2, V2, Wo2);
  k_attn<<<512, 256, 0, stream>>>(Q2, K2, V2, PA, ML2);
  k_merge<<<512, 256, 0, stream>>>(PA, ML2, Wo2, bo, (float*)d_out);
}